// Round 12
// baseline (2769.592 us; speedup 1.0000x reference)
//
#include <hip/hip_runtime.h>
#include <math.h>

#define B 4
#define C 200
#define H 128
#define W 128
#define N 16384   // H*W
#define K 256
#define ITERS 5
#define FACT 1.25f   // COMPACTNESS / S = 10 / 8
#define NT 32        // split-K factor for the update GEMM

// workspace layout (floats)
#define OFF_A2    0
#define OFF_CS    (OFF_A2 + B*N)            // 65536
#define OFF_CSPAT (OFF_CS + B*K*C)          // 270336
#define OFF_B2    (OFF_CSPAT + B*K*2)       // 272384
#define OFF_SACC  (OFF_B2 + B*K)            // 273408
#define OFF_MACC  (OFF_SACC + B*K*C)        // 478208
#define OFF_SPACC (OFF_MACC + B*K)          // 479232
#define OFF_PART  (OFF_SPACC + B*K*2)       // 481280
#define PART_SZ   (B*NT*8*25*K)             // 6,553,600 floats (26.2 MB)
#define OFF_MPART (OFF_PART + PART_SZ)
#define MPART_SZ  (B*NT*3*K)                // 98,304 floats
#define WS_NEED   ((size_t)(OFF_MPART + MPART_SZ) * 4)

// ---------------------------------------------------------------------------
// init: centers_spectral[b,k,c] = x[0,c,seed_n(k)]; centers_spatial = grid
__global__ void k_init(const float* __restrict__ x, float* __restrict__ cs,
                       float* __restrict__ cspat) {
  int k = blockIdx.x, c = threadIdx.x;
  int i = k >> 4, j = k & 15;
  int sn = (4 + 8*i)*W + (4 + 8*j);
  if (c < C) {
    float v = x[(size_t)c*N + sn];
    for (int b = 0; b < B; ++b) cs[((size_t)(b*K + k))*C + c] = v;
  }
  if (c == 0) {
    for (int b = 0; b < B; ++b) {
      cspat[(b*K + k)*2 + 0] = (float)(4 + 8*i);
      cspat[(b*K + k)*2 + 1] = (float)(4 + 8*j);
    }
  }
}

// a2[b,n] = sum_c x[b,c,n]^2  (iteration-invariant)
__global__ void k_a2(const float* __restrict__ x, float* __restrict__ a2) {
  int b = blockIdx.x >> 6;
  int n = ((blockIdx.x & 63) << 8) + threadIdx.x;
  const float* xp = x + (size_t)b*C*N + n;
  float s = 0.f;
  #pragma unroll 8
  for (int c = 0; c < C; ++c) { float v = xp[(size_t)c*N]; s += v*v; }
  a2[b*N + n] = s;
}

// b2[b,k] = sum_c cs[b,k,c]^2
__global__ void k_b2(const float* __restrict__ cs, float* __restrict__ b2) {
  int bk = blockIdx.x;
  const float* p = cs + (size_t)bk*C;
  float s = 0.f;
  for (int c = threadIdx.x; c < C; c += 64) { float v = p[c]; s += v*v; }
  for (int off = 32; off > 0; off >>= 1) s += __shfl_down(s, off);
  if (threadIdx.x == 0) b2[bk] = s;
}

// ---------------------------------------------------------------------------
// assignment v7: v6 work assignment (16 waves; wave owns 16 k's; lane owns
// 2 pixels; block = 128 pixels x 256 k) + LDS padded to 82,944 B so only ONE
// block fits per CU -> 16 waves/CU = 4 waves/SIMD -> VGPR budget 128 (the
// compiler's VGPR target follows LDS-implied occupancy; at 74.7KB it fit 2
// blocks -> 8 waves/SIMD -> 64 VGPR -> spill, R11).
__global__ __launch_bounds__(1024, 1) void k_assign(
    const float* __restrict__ x, const float* __restrict__ cs,
    const float* __restrict__ cspat, const float* __restrict__ b2,
    const float* __restrict__ a2, float* __restrict__ Q) {
  __shared__ float cs_lds[K*40];    // 40960 B [k][40]
  __shared__ float x_lds[128*44];   // 22528 B [pix][44] (40 used)
  __shared__ float b2s[K], cys[K], cxs[K];   // 3072 B
  __shared__ float red[16*128*2];   // 16384 B [kg][pix] (2x occupancy pad)

  int b   = blockIdx.x >> 7;          // 128 blocks per batch
  int n0  = (blockIdx.x & 127) << 7;  // 128 pixels per block
  int tid = threadIdx.x;
  int kg  = __builtin_amdgcn_readfirstlane(tid >> 6);  // wave-uniform 0..15
  int lane = tid & 63;
  int pix0 = lane, pix1 = lane + 64;

  if (tid < K) {
    b2s[tid] = b2[b*K + tid];
    cys[tid] = cspat[(b*K + tid)*2 + 0];
    cxs[tid] = cspat[(b*K + tid)*2 + 1];
  }

  float acc0[16], acc1[16];
  #pragma unroll
  for (int kq = 0; kq < 16; ++kq) { acc0[kq] = 0.f; acc1[kq] = 0.f; }

  const float* xb  = x  + (size_t)b*C*N;
  const float* csb = cs + (size_t)b*K*C;

  int crow = tid >> 1, chalf = (tid & 1) * 20;   // cs staging (waves 0-7)
  int xtid = tid - 512;                          // x staging (waves 8-15)

  for (int t = 0; t < 5; ++t) {
    int cc0 = t * 40;
    __syncthreads();   // previous tile's readers done (also covers b2s init)
    if (tid < 512) {   // stage cs [256][40]: 2 threads/row, 5 float4 each
      const float* src = csb + (size_t)crow*C + cc0 + chalf;
      float* dst = &cs_lds[crow*40 + chalf];
      #pragma unroll
      for (int m = 0; m < 5; ++m)
        *(float4*)&dst[m*4] = *(const float4*)&src[m*4];
    } else {           // stage x [128 pix][40 c]
      #pragma unroll
      for (int pass = 0; pass < 10; ++pass) {
        int idx = pass*512 + xtid;
        int p = idx & 127, ci = idx >> 7;
        x_lds[p*44 + ci] = xb[(size_t)(cc0 + ci)*N + n0 + p];
      }
    }
    __syncthreads();
    #pragma unroll
    for (int cc4 = 0; cc4 < 10; ++cc4) {
      float4 xa = *(const float4*)&x_lds[pix0*44 + cc4*4];
      float4 xc = *(const float4*)&x_lds[pix1*44 + cc4*4];
      #pragma unroll
      for (int kq = 0; kq < 16; ++kq) {
        float4 cv = *(const float4*)&cs_lds[(kg*16 + kq)*40 + cc4*4]; // broadcast
        float a = acc0[kq];
        a = fmaf(xa.x, cv.x, a);
        a = fmaf(xa.y, cv.y, a);
        a = fmaf(xa.z, cv.z, a);
        a = fmaf(xa.w, cv.w, a);
        acc0[kq] = a;
        float e = acc1[kq];
        e = fmaf(xc.x, cv.x, e);
        e = fmaf(xc.y, cv.y, e);
        e = fmaf(xc.z, cv.z, e);
        e = fmaf(xc.w, cv.w, e);
        acc1[kq] = e;
      }
    }
  }

  // ---- distances + softmax over K (cross-kgroup via LDS) ----
  int na = n0 + pix0, nb_ = n0 + pix1;
  float a2v0 = a2[b*N + na];
  float a2v1 = a2[b*N + nb_];
  float py = (float)(na >> 7);            // both pixels share the image row
  float px0f = (float)(na & 127), px1f = (float)(nb_ & 127);

  float mn0 = 1e30f, mn1 = 1e30f;
  #pragma unroll
  for (int kq = 0; kq < 16; ++kq) {
    int k = kg*16 + kq;
    float b2v = b2s[k];           // uniform addr -> broadcast
    float cy = cys[k], cx = cxs[k];
    float dy = py - cy;
    float dx0 = px0f - cx, dx1 = px1f - cx;
    float d0 = sqrtf(fmaxf(a2v0 + b2v - 2.f*acc0[kq], 1e-12f))
             + FACT*sqrtf(fmaxf(dy*dy + dx0*dx0, 1e-12f));
    float d1 = sqrtf(fmaxf(a2v1 + b2v - 2.f*acc1[kq], 1e-12f))
             + FACT*sqrtf(fmaxf(dy*dy + dx1*dx1, 1e-12f));
    acc0[kq] = d0; acc1[kq] = d1;
    mn0 = fminf(mn0, d0); mn1 = fminf(mn1, d1);
  }
  red[kg*128 + pix0] = mn0;
  red[kg*128 + pix1] = mn1;
  __syncthreads();
  #pragma unroll
  for (int g = 0; g < 16; ++g) {
    mn0 = fminf(mn0, red[g*128 + pix0]);
    mn1 = fminf(mn1, red[g*128 + pix1]);
  }
  float s0 = 0.f, s1 = 0.f;
  #pragma unroll
  for (int kq = 0; kq < 16; ++kq) {
    float e0 = __expf(mn0 - acc0[kq]);
    float e1 = __expf(mn1 - acc1[kq]);
    acc0[kq] = e0; acc1[kq] = e1;
    s0 += e0; s1 += e1;
  }
  __syncthreads();   // min-phase reads done before overwrite
  red[kg*128 + pix0] = s0;
  red[kg*128 + pix1] = s1;
  __syncthreads();
  s0 = 0.f; s1 = 0.f;
  #pragma unroll
  for (int g = 0; g < 16; ++g) {
    s0 += red[g*128 + pix0];
    s1 += red[g*128 + pix1];
  }
  float inv0 = 1.f / s0, inv1 = 1.f / s1;

  float* q0 = Q + ((size_t)(b*N + na))*K + kg*16;
  float* q1 = Q + ((size_t)(b*N + nb_))*K + kg*16;
  #pragma unroll
  for (int m = 0; m < 4; ++m) {
    float4 v0 = make_float4(acc0[m*4]*inv0, acc0[m*4+1]*inv0,
                            acc0[m*4+2]*inv0, acc0[m*4+3]*inv0);
    *(float4*)&q0[m*4] = v0;
  }
  #pragma unroll
  for (int m = 0; m < 4; ++m) {
    float4 v1 = make_float4(acc1[m*4]*inv1, acc1[m*4+1]*inv1,
                            acc1[m*4+2]*inv1, acc1[m*4+3]*inv1);
    *(float4*)&q1[m*4] = v1;
  }
}

// ---------------------------------------------------------------------------
// update v4 stage 1 (split-K, NO atomics): thread owns k=tid, 25 c's.
// Each block (b, ct, nt) accumulates over its 512-n slice and stores partials
// to a private workspace slice: part[(b*NT+nt)*8+ct][c][k]  (k contiguous).
__global__ __launch_bounds__(256) void k_update2(
    const float* __restrict__ x, const float* __restrict__ Q,
    float* __restrict__ part, float* __restrict__ mpart) {
  __shared__ float x_lds[32*28];    // [n][c] 25 used, pad 28
  int bid = blockIdx.x;             // B*8*NT = 1024
  int b  = bid >> 8;
  int ct = (bid >> 5) & 7;          // 0..7
  int nt = bid & 31;                // 0..31
  int tid = threadIdx.x;
  int c0 = ct * 25;

  float acc[25];
  #pragma unroll
  for (int c = 0; c < 25; ++c) acc[c] = 0.f;
  float mass = 0.f, sy = 0.f, sx = 0.f;

  const float* xb = x + (size_t)b*C*N + (size_t)c0*N;
  const float* Qb = Q + (size_t)b*N*K;

  for (int ch = 0; ch < 16; ++ch) {
    int nb = nt*512 + ch*32;
    __syncthreads();
    #pragma unroll
    for (int pass = 0; pass < 4; ++pass) {  // stage x [25c][32n] -> [n][c]
      int idx = pass*256 + tid;
      if (idx < 800) {
        int ci = idx >> 5, nn = idx & 31;
        x_lds[nn*28 + ci] = xb[(size_t)ci*N + nb + nn];
      }
    }
    __syncthreads();
    float py  = (float)(nb >> 7);        // 32-n chunk stays in one image row
    float pxb = (float)(nb & 127);
    #pragma unroll
    for (int n4 = 0; n4 < 8; ++n4) {
      float qv[4];
      #pragma unroll
      for (int j = 0; j < 4; ++j)        // independent coalesced loads
        qv[j] = Qb[(size_t)(nb + n4*4 + j)*K + tid];
      #pragma unroll
      for (int j = 0; j < 4; ++j) {
        int nn = n4*4 + j;
        float q = qv[j];
        if (ct == 0) {
          mass += q;
          sy += q * py;
          sx += q * (pxb + (float)nn);
        }
        const float* xr = &x_lds[nn*28];   // wave-uniform -> broadcast
        #pragma unroll
        for (int c4 = 0; c4 < 6; ++c4) {
          float4 xv = *(const float4*)&xr[c4*4];
          acc[c4*4+0] = fmaf(q, xv.x, acc[c4*4+0]);
          acc[c4*4+1] = fmaf(q, xv.y, acc[c4*4+1]);
          acc[c4*4+2] = fmaf(q, xv.z, acc[c4*4+2]);
          acc[c4*4+3] = fmaf(q, xv.w, acc[c4*4+3]);
        }
        acc[24] = fmaf(q, xr[24], acc[24]);
      }
    }
  }
  // plain coalesced stores, no atomics
  float* pp = part + ((size_t)((b*NT + nt)*8 + ct) * 25) * K;
  #pragma unroll
  for (int c = 0; c < 25; ++c) pp[c*K + tid] = acc[c];
  if (ct == 0) {
    float* mp = mpart + (size_t)(b*NT + nt) * 3 * K;
    mp[tid]       = mass;
    mp[K + tid]   = sy;
    mp[2*K + tid] = sx;
  }
}

// update v4 stage 2: reduce NT partials per output element. grid = B*8*25.
__global__ __launch_bounds__(256) void k_reduce(
    const float* __restrict__ part, const float* __restrict__ mpart,
    float* __restrict__ sacc, float* __restrict__ macc,
    float* __restrict__ spacc) {
  int bid = blockIdx.x;        // B * 200
  int b = bid / 200;
  int r = bid % 200;
  int ct = r / 25, c = r % 25;
  int tid = threadIdx.x;
  float s = 0.f;
  for (int nt = 0; nt < NT; ++nt)
    s += part[((size_t)((b*NT + nt)*8 + ct) * 25 + c) * K + tid];
  sacc[(size_t)(b*K + tid)*C + ct*25 + c] = s;
  if (ct == 0 && c == 0) {
    float m = 0.f, yy = 0.f, xx = 0.f;
    for (int nt = 0; nt < NT; ++nt) {
      const float* mp = mpart + (size_t)(b*NT + nt) * 3 * K;
      m  += mp[tid];
      yy += mp[K + tid];
      xx += mp[2*K + tid];
    }
    macc[b*K + tid] = m;
    spacc[(b*K + tid)*2 + 0] = yy;
    spacc[(b*K + tid)*2 + 1] = xx;
  }
}

// ---------------------------------------------------------------------------
// fallback update (atomic version, used only if ws too small for partials)
__global__ __launch_bounds__(256, 2) void k_update(
    const float* __restrict__ x, const float* __restrict__ Q,
    float* __restrict__ sacc, float* __restrict__ macc,
    float* __restrict__ spacc) {
  __shared__ float x_lds[32*28];
  int bid = blockIdx.x;
  int b = bid >> 9;
  int rest = bid & 511;
  int ct = rest >> 6;
  int nt = rest & 63;
  int tid = threadIdx.x;
  int c0 = ct * 25;

  float acc[25];
  #pragma unroll
  for (int c = 0; c < 25; ++c) acc[c] = 0.f;
  float mass = 0.f, sy = 0.f, sx = 0.f;

  const float* xb = x + (size_t)b*C*N + (size_t)c0*N;
  const float* Qb = Q + (size_t)b*N*K;

  for (int ch = 0; ch < 8; ++ch) {
    int nb = nt*256 + ch*32;
    __syncthreads();
    #pragma unroll
    for (int pass = 0; pass < 4; ++pass) {
      int idx = pass*256 + tid;
      if (idx < 800) {
        int ci = idx >> 5, nn = idx & 31;
        x_lds[nn*28 + ci] = xb[(size_t)ci*N + nb + nn];
      }
    }
    __syncthreads();
    float py  = (float)(nb >> 7);
    float pxb = (float)(nb & 127);
    #pragma unroll
    for (int n4 = 0; n4 < 8; ++n4) {
      float qv[4];
      #pragma unroll
      for (int j = 0; j < 4; ++j)
        qv[j] = Qb[(size_t)(nb + n4*4 + j)*K + tid];
      #pragma unroll
      for (int j = 0; j < 4; ++j) {
        int nn = n4*4 + j;
        float q = qv[j];
        if (ct == 0) {
          mass += q;
          sy += q * py;
          sx += q * (pxb + (float)nn);
        }
        const float* xr = &x_lds[nn*28];
        #pragma unroll
        for (int c4 = 0; c4 < 6; ++c4) {
          float4 xv = *(const float4*)&xr[c4*4];
          acc[c4*4+0] = fmaf(q, xv.x, acc[c4*4+0]);
          acc[c4*4+1] = fmaf(q, xv.y, acc[c4*4+1]);
          acc[c4*4+2] = fmaf(q, xv.z, acc[c4*4+2]);
          acc[c4*4+3] = fmaf(q, xv.w, acc[c4*4+3]);
        }
        acc[24] = fmaf(q, xr[24], acc[24]);
      }
    }
  }
  float* sp = sacc + ((size_t)(b*K + tid))*C + c0;
  #pragma unroll
  for (int c = 0; c < 25; ++c) atomicAdd(&sp[c], acc[c]);
  if (ct == 0) {
    atomicAdd(&macc[b*K + tid], mass);
    atomicAdd(&spacc[(b*K + tid)*2 + 0], sy);
    atomicAdd(&spacc[(b*K + tid)*2 + 1], sx);
  }
}

// finalize: divide by mass; write centers (and to d_out tail on last iter)
__global__ void k_final(const float* __restrict__ sacc, const float* __restrict__ macc,
                        const float* __restrict__ spacc, float* __restrict__ cs,
                        float* __restrict__ cspat, float* __restrict__ outc, int last) {
  int bk = blockIdx.x;
  int c = threadIdx.x;
  float inv = 1.f / (macc[bk] + 1e-6f);
  if (c < C) {
    float v = sacc[(size_t)bk*C + c] * inv;
    cs[(size_t)bk*C + c] = v;
    if (last) outc[(size_t)bk*C + c] = v;
  } else if (c == C) {
    cspat[bk*2 + 0] = spacc[bk*2 + 0] * inv;
  } else if (c == C + 1) {
    cspat[bk*2 + 1] = spacc[bk*2 + 1] * inv;
  }
}

extern "C" void kernel_launch(void* const* d_in, const int* in_sizes, int n_in,
                              void* d_out, int out_size, void* d_ws, size_t ws_size,
                              hipStream_t stream) {
  const float* x = (const float*)d_in[0];
  float* out = (float*)d_out;
  float* ws  = (float*)d_ws;
  float* a2    = ws + OFF_A2;
  float* cs    = ws + OFF_CS;
  float* cspat = ws + OFF_CSPAT;
  float* b2    = ws + OFF_B2;
  float* sacc  = ws + OFF_SACC;
  float* macc  = ws + OFF_MACC;
  float* spacc = ws + OFF_SPACC;
  float* part  = ws + OFF_PART;
  float* mpart = ws + OFF_MPART;
  float* outc  = out + (size_t)B*N*K;
  int split = (ws_size >= WS_NEED) ? 1 : 0;

  hipLaunchKernelGGL(k_init, dim3(K), dim3(256), 0, stream, x, cs, cspat);
  hipLaunchKernelGGL(k_a2, dim3(B*64), dim3(256), 0, stream, x, a2);
  for (int it = 0; it < ITERS; ++it) {
    hipLaunchKernelGGL(k_b2, dim3(B*K), dim3(64), 0, stream, cs, b2);
    hipLaunchKernelGGL(k_assign, dim3(B*128), dim3(1024), 0, stream,
                       x, cs, cspat, b2, a2, out);
    if (split) {
      hipLaunchKernelGGL(k_update2, dim3(B*8*NT), dim3(256), 0, stream,
                         x, out, part, mpart);
      hipLaunchKernelGGL(k_reduce, dim3(B*200), dim3(256), 0, stream,
                         part, mpart, sacc, macc, spacc);
    } else {
      hipMemsetAsync(sacc, 0, (size_t)(B*K*C + B*K + B*K*2)*sizeof(float), stream);
      hipLaunchKernelGGL(k_update, dim3(B*512), dim3(256), 0, stream,
                         x, out, sacc, macc, spacc);
    }
    hipLaunchKernelGGL(k_final, dim3(B*K), dim3(256), 0, stream,
                       sacc, macc, spacc, cs, cspat, outc, (it == ITERS-1) ? 1 : 0);
  }
}

// Round 13
// 2461.768 us; speedup vs baseline: 1.1250x; 1.1250x over previous
//
#include <hip/hip_runtime.h>
#include <math.h>

#define B 4
#define C 200
#define H 128
#define W 128
#define N 16384   // H*W
#define K 256
#define ITERS 5
#define FACT 1.25f   // COMPACTNESS / S = 10 / 8
#define NT 32        // split-K factor for the update GEMM

// workspace layout (floats)
#define OFF_A2    0
#define OFF_CS    (OFF_A2 + B*N)            // 65536
#define OFF_CSPAT (OFF_CS + B*K*C)          // 270336
#define OFF_B2    (OFF_CSPAT + B*K*2)       // 272384
#define OFF_SACC  (OFF_B2 + B*K)            // 273408
#define OFF_MACC  (OFF_SACC + B*K*C)        // 478208
#define OFF_SPACC (OFF_MACC + B*K)          // 479232
#define OFF_PART  (OFF_SPACC + B*K*2)       // 481280
#define PART_SZ   (B*NT*8*25*K)             // 6,553,600 floats (26.2 MB)
#define OFF_MPART (OFF_PART + PART_SZ)
#define MPART_SZ  (B*NT*3*K)                // 98,304 floats
#define WS_NEED   ((size_t)(OFF_MPART + MPART_SZ) * 4)

// ---------------------------------------------------------------------------
// init: centers_spectral[b,k,c] = x[0,c,seed_n(k)]; centers_spatial = grid
__global__ void k_init(const float* __restrict__ x, float* __restrict__ cs,
                       float* __restrict__ cspat) {
  int k = blockIdx.x, c = threadIdx.x;
  int i = k >> 4, j = k & 15;
  int sn = (4 + 8*i)*W + (4 + 8*j);
  if (c < C) {
    float v = x[(size_t)c*N + sn];
    for (int b = 0; b < B; ++b) cs[((size_t)(b*K + k))*C + c] = v;
  }
  if (c == 0) {
    for (int b = 0; b < B; ++b) {
      cspat[(b*K + k)*2 + 0] = (float)(4 + 8*i);
      cspat[(b*K + k)*2 + 1] = (float)(4 + 8*j);
    }
  }
}

// a2[b,n] = sum_c x[b,c,n]^2  (iteration-invariant)
__global__ void k_a2(const float* __restrict__ x, float* __restrict__ a2) {
  int b = blockIdx.x >> 6;
  int n = ((blockIdx.x & 63) << 8) + threadIdx.x;
  const float* xp = x + (size_t)b*C*N + n;
  float s = 0.f;
  #pragma unroll 8
  for (int c = 0; c < C; ++c) { float v = xp[(size_t)c*N]; s += v*v; }
  a2[b*N + n] = s;
}

// b2[b,k] = sum_c cs[b,k,c]^2
__global__ void k_b2(const float* __restrict__ cs, float* __restrict__ b2) {
  int bk = blockIdx.x;
  const float* p = cs + (size_t)bk*C;
  float s = 0.f;
  for (int c = threadIdx.x; c < C; c += 64) { float v = p[c]; s += v*v; }
  for (int off = 32; off > 0; off >>= 1) s += __shfl_down(s, off);
  if (threadIdx.x == 0) b2[bk] = s;
}

// ---------------------------------------------------------------------------
// assignment v8: v4 geometry (512 thr = 8 waves; wave == kgroup of 32 k;
// 1 pixel/lane; launch_bounds(512,2) -> proven VGPR 128, no spill) with
// CONFLICT-FREE LDS layouts:
//  - cs tile staged as a LINEAR copy (lane-consecutive float4 writes);
//    main-loop cs reads are wave-uniform b128 -> broadcast (free).
//  - x tile stored [c][64] so both staging writes and main-loop reads are
//    lane-stride-1 scalars (conflict-free).  (v4's [pix][44] was 8-way.)
__global__ __launch_bounds__(512, 2) void k_assign(
    const float* __restrict__ x, const float* __restrict__ cs,
    const float* __restrict__ cspat, const float* __restrict__ b2,
    const float* __restrict__ a2, float* __restrict__ Q) {
  __shared__ float cs_lds[K*40];    // 40960 B, rows [k][40] but staged linearly
  __shared__ float x_lds[40*64];    // 10240 B, [c][pix]
  __shared__ float b2s[K], cys[K], cxs[K];
  __shared__ float red[512];        // [kg][pix]

  int b   = blockIdx.x >> 8;          // 256 blocks per batch
  int n0  = (blockIdx.x & 255) << 6;  // 64 pixels per block
  int tid = threadIdx.x;
  int kg  = __builtin_amdgcn_readfirstlane(tid >> 6);  // wave-uniform 0..7
  int pix = tid & 63;

  if (tid < K) {
    b2s[tid] = b2[b*K + tid];
    cys[tid] = cspat[(b*K + tid)*2 + 0];
    cxs[tid] = cspat[(b*K + tid)*2 + 1];
  }

  float acc[32];
  #pragma unroll
  for (int kq = 0; kq < 32; ++kq) acc[kq] = 0.f;

  const float* xb  = x  + (size_t)b*C*N;
  const float* csb = cs + (size_t)b*K*C;
  float4* cs_lds4 = (float4*)cs_lds;

  for (int t = 0; t < 5; ++t) {
    int cc0 = t * 40;
    __syncthreads();   // previous tile's readers done (also covers b2s init)
    #pragma unroll
    for (int pass = 0; pass < 5; ++pass) {   // cs tile: linear copy, 2560 f4
      int f = pass*512 + tid;                // f = k*10 + j
      int k = f / 10, j = f - k*10;
      cs_lds4[f] = *(const float4*)&csb[(size_t)k*C + cc0 + j*4];
    }
    #pragma unroll
    for (int pass = 0; pass < 5; ++pass) {   // x tile [40c][64p], stride-1
      int idx = pass*512 + tid;
      int ci = idx >> 6, p = idx & 63;
      x_lds[ci*64 + p] = xb[(size_t)(cc0 + ci)*N + n0 + p];
    }
    __syncthreads();
    #pragma unroll
    for (int cc4 = 0; cc4 < 10; ++cc4) {
      float xs0 = x_lds[(cc4*4 + 0)*64 + pix];   // lane-stride-1, no conflict
      float xs1 = x_lds[(cc4*4 + 1)*64 + pix];
      float xs2 = x_lds[(cc4*4 + 2)*64 + pix];
      float xs3 = x_lds[(cc4*4 + 3)*64 + pix];
      #pragma unroll
      for (int kq = 0; kq < 32; ++kq) {
        float4 cv = *(const float4*)&cs_lds[(kg*32 + kq)*40 + cc4*4]; // broadcast
        float a = acc[kq];
        a = fmaf(xs0, cv.x, a);
        a = fmaf(xs1, cv.y, a);
        a = fmaf(xs2, cv.z, a);
        a = fmaf(xs3, cv.w, a);
        acc[kq] = a;
      }
    }
  }

  // ---- distances + softmax over K (cross-kgroup via LDS) ----
  int n = n0 + pix;
  float a2v = a2[b*N + n];
  float py = (float)(n >> 7), px = (float)(n & 127);

  float mn = 1e30f;
  #pragma unroll
  for (int kq = 0; kq < 32; ++kq) {
    int k = kg*32 + kq;
    float b2v = b2s[k];           // uniform addr -> broadcast
    float dy = py - cys[k], dx = px - cxs[k];
    float d = sqrtf(fmaxf(a2v + b2v - 2.f*acc[kq], 1e-12f))
            + FACT*sqrtf(fmaxf(dy*dy + dx*dx, 1e-12f));
    acc[kq] = d;
    mn = fminf(mn, d);
  }
  red[kg*64 + pix] = mn;
  __syncthreads();
  #pragma unroll
  for (int g = 0; g < 8; ++g) mn = fminf(mn, red[g*64 + pix]);

  float s = 0.f;
  #pragma unroll
  for (int kq = 0; kq < 32; ++kq) {
    float e = __expf(mn - acc[kq]);
    acc[kq] = e;
    s += e;
  }
  __syncthreads();   // min-phase reads done before overwrite
  red[kg*64 + pix] = s;
  __syncthreads();
  s = 0.f;
  #pragma unroll
  for (int g = 0; g < 8; ++g) s += red[g*64 + pix];
  float inv = 1.f / s;

  float* q = Q + ((size_t)(b*N + n))*K + kg*32;
  #pragma unroll
  for (int m = 0; m < 8; ++m) {
    float4 v = make_float4(acc[m*4]*inv, acc[m*4+1]*inv,
                           acc[m*4+2]*inv, acc[m*4+3]*inv);
    *(float4*)&q[m*4] = v;
  }
}

// ---------------------------------------------------------------------------
// update v4 stage 1 (split-K, NO atomics): thread owns k=tid, 25 c's.
// Each block (b, ct, nt) accumulates over its 512-n slice and stores partials
// to a private workspace slice: part[(b*NT+nt)*8+ct][c][k]  (k contiguous).
__global__ __launch_bounds__(256) void k_update2(
    const float* __restrict__ x, const float* __restrict__ Q,
    float* __restrict__ part, float* __restrict__ mpart) {
  __shared__ float x_lds[32*28];    // [n][c] 25 used, pad 28
  int bid = blockIdx.x;             // B*8*NT = 1024
  int b  = bid >> 8;
  int ct = (bid >> 5) & 7;          // 0..7
  int nt = bid & 31;                // 0..31
  int tid = threadIdx.x;
  int c0 = ct * 25;

  float acc[25];
  #pragma unroll
  for (int c = 0; c < 25; ++c) acc[c] = 0.f;
  float mass = 0.f, sy = 0.f, sx = 0.f;

  const float* xb = x + (size_t)b*C*N + (size_t)c0*N;
  const float* Qb = Q + (size_t)b*N*K;

  for (int ch = 0; ch < 16; ++ch) {
    int nb = nt*512 + ch*32;
    __syncthreads();
    #pragma unroll
    for (int pass = 0; pass < 4; ++pass) {  // stage x [25c][32n] -> [n][c]
      int idx = pass*256 + tid;
      if (idx < 800) {
        int ci = idx >> 5, nn = idx & 31;
        x_lds[nn*28 + ci] = xb[(size_t)ci*N + nb + nn];
      }
    }
    __syncthreads();
    float py  = (float)(nb >> 7);        // 32-n chunk stays in one image row
    float pxb = (float)(nb & 127);
    #pragma unroll
    for (int n4 = 0; n4 < 8; ++n4) {
      float qv[4];
      #pragma unroll
      for (int j = 0; j < 4; ++j)        // independent coalesced loads
        qv[j] = Qb[(size_t)(nb + n4*4 + j)*K + tid];
      #pragma unroll
      for (int j = 0; j < 4; ++j) {
        int nn = n4*4 + j;
        float q = qv[j];
        if (ct == 0) {
          mass += q;
          sy += q * py;
          sx += q * (pxb + (float)nn);
        }
        const float* xr = &x_lds[nn*28];   // wave-uniform -> broadcast
        #pragma unroll
        for (int c4 = 0; c4 < 6; ++c4) {
          float4 xv = *(const float4*)&xr[c4*4];
          acc[c4*4+0] = fmaf(q, xv.x, acc[c4*4+0]);
          acc[c4*4+1] = fmaf(q, xv.y, acc[c4*4+1]);
          acc[c4*4+2] = fmaf(q, xv.z, acc[c4*4+2]);
          acc[c4*4+3] = fmaf(q, xv.w, acc[c4*4+3]);
        }
        acc[24] = fmaf(q, xr[24], acc[24]);
      }
    }
  }
  // plain coalesced stores, no atomics
  float* pp = part + ((size_t)((b*NT + nt)*8 + ct) * 25) * K;
  #pragma unroll
  for (int c = 0; c < 25; ++c) pp[c*K + tid] = acc[c];
  if (ct == 0) {
    float* mp = mpart + (size_t)(b*NT + nt) * 3 * K;
    mp[tid]       = mass;
    mp[K + tid]   = sy;
    mp[2*K + tid] = sx;
  }
}

// update v4 stage 2: reduce NT partials per output element. grid = B*8*25.
__global__ __launch_bounds__(256) void k_reduce(
    const float* __restrict__ part, const float* __restrict__ mpart,
    float* __restrict__ sacc, float* __restrict__ macc,
    float* __restrict__ spacc) {
  int bid = blockIdx.x;        // B * 200
  int b = bid / 200;
  int r = bid % 200;
  int ct = r / 25, c = r % 25;
  int tid = threadIdx.x;
  float s = 0.f;
  for (int nt = 0; nt < NT; ++nt)
    s += part[((size_t)((b*NT + nt)*8 + ct) * 25 + c) * K + tid];
  sacc[(size_t)(b*K + tid)*C + ct*25 + c] = s;
  if (ct == 0 && c == 0) {
    float m = 0.f, yy = 0.f, xx = 0.f;
    for (int nt = 0; nt < NT; ++nt) {
      const float* mp = mpart + (size_t)(b*NT + nt) * 3 * K;
      m  += mp[tid];
      yy += mp[K + tid];
      xx += mp[2*K + tid];
    }
    macc[b*K + tid] = m;
    spacc[(b*K + tid)*2 + 0] = yy;
    spacc[(b*K + tid)*2 + 1] = xx;
  }
}

// ---------------------------------------------------------------------------
// fallback update (atomic version, used only if ws too small for partials)
__global__ __launch_bounds__(256, 2) void k_update(
    const float* __restrict__ x, const float* __restrict__ Q,
    float* __restrict__ sacc, float* __restrict__ macc,
    float* __restrict__ spacc) {
  __shared__ float x_lds[32*28];
  int bid = blockIdx.x;
  int b = bid >> 9;
  int rest = bid & 511;
  int ct = rest >> 6;
  int nt = rest & 63;
  int tid = threadIdx.x;
  int c0 = ct * 25;

  float acc[25];
  #pragma unroll
  for (int c = 0; c < 25; ++c) acc[c] = 0.f;
  float mass = 0.f, sy = 0.f, sx = 0.f;

  const float* xb = x + (size_t)b*C*N + (size_t)c0*N;
  const float* Qb = Q + (size_t)b*N*K;

  for (int ch = 0; ch < 8; ++ch) {
    int nb = nt*256 + ch*32;
    __syncthreads();
    #pragma unroll
    for (int pass = 0; pass < 4; ++pass) {
      int idx = pass*256 + tid;
      if (idx < 800) {
        int ci = idx >> 5, nn = idx & 31;
        x_lds[nn*28 + ci] = xb[(size_t)ci*N + nb + nn];
      }
    }
    __syncthreads();
    float py  = (float)(nb >> 7);
    float pxb = (float)(nb & 127);
    #pragma unroll
    for (int n4 = 0; n4 < 8; ++n4) {
      float qv[4];
      #pragma unroll
      for (int j = 0; j < 4; ++j)
        qv[j] = Qb[(size_t)(nb + n4*4 + j)*K + tid];
      #pragma unroll
      for (int j = 0; j < 4; ++j) {
        int nn = n4*4 + j;
        float q = qv[j];
        if (ct == 0) {
          mass += q;
          sy += q * py;
          sx += q * (pxb + (float)nn);
        }
        const float* xr = &x_lds[nn*28];
        #pragma unroll
        for (int c4 = 0; c4 < 6; ++c4) {
          float4 xv = *(const float4*)&xr[c4*4];
          acc[c4*4+0] = fmaf(q, xv.x, acc[c4*4+0]);
          acc[c4*4+1] = fmaf(q, xv.y, acc[c4*4+1]);
          acc[c4*4+2] = fmaf(q, xv.z, acc[c4*4+2]);
          acc[c4*4+3] = fmaf(q, xv.w, acc[c4*4+3]);
        }
        acc[24] = fmaf(q, xr[24], acc[24]);
      }
    }
  }
  float* sp = sacc + ((size_t)(b*K + tid))*C + c0;
  #pragma unroll
  for (int c = 0; c < 25; ++c) atomicAdd(&sp[c], acc[c]);
  if (ct == 0) {
    atomicAdd(&macc[b*K + tid], mass);
    atomicAdd(&spacc[(b*K + tid)*2 + 0], sy);
    atomicAdd(&spacc[(b*K + tid)*2 + 1], sx);
  }
}

// finalize: divide by mass; write centers (and to d_out tail on last iter)
__global__ void k_final(const float* __restrict__ sacc, const float* __restrict__ macc,
                        const float* __restrict__ spacc, float* __restrict__ cs,
                        float* __restrict__ cspat, float* __restrict__ outc, int last) {
  int bk = blockIdx.x;
  int c = threadIdx.x;
  float inv = 1.f / (macc[bk] + 1e-6f);
  if (c < C) {
    float v = sacc[(size_t)bk*C + c] * inv;
    cs[(size_t)bk*C + c] = v;
    if (last) outc[(size_t)bk*C + c] = v;
  } else if (c == C) {
    cspat[bk*2 + 0] = spacc[bk*2 + 0] * inv;
  } else if (c == C + 1) {
    cspat[bk*2 + 1] = spacc[bk*2 + 1] * inv;
  }
}

extern "C" void kernel_launch(void* const* d_in, const int* in_sizes, int n_in,
                              void* d_out, int out_size, void* d_ws, size_t ws_size,
                              hipStream_t stream) {
  const float* x = (const float*)d_in[0];
  float* out = (float*)d_out;
  float* ws  = (float*)d_ws;
  float* a2    = ws + OFF_A2;
  float* cs    = ws + OFF_CS;
  float* cspat = ws + OFF_CSPAT;
  float* b2    = ws + OFF_B2;
  float* sacc  = ws + OFF_SACC;
  float* macc  = ws + OFF_MACC;
  float* spacc = ws + OFF_SPACC;
  float* part  = ws + OFF_PART;
  float* mpart = ws + OFF_MPART;
  float* outc  = out + (size_t)B*N*K;
  int split = (ws_size >= WS_NEED) ? 1 : 0;

  hipLaunchKernelGGL(k_init, dim3(K), dim3(256), 0, stream, x, cs, cspat);
  hipLaunchKernelGGL(k_a2, dim3(B*64), dim3(256), 0, stream, x, a2);
  for (int it = 0; it < ITERS; ++it) {
    hipLaunchKernelGGL(k_b2, dim3(B*K), dim3(64), 0, stream, cs, b2);
    hipLaunchKernelGGL(k_assign, dim3(B*256), dim3(512), 0, stream,
                       x, cs, cspat, b2, a2, out);
    if (split) {
      hipLaunchKernelGGL(k_update2, dim3(B*8*NT), dim3(256), 0, stream,
                         x, out, part, mpart);
      hipLaunchKernelGGL(k_reduce, dim3(B*200), dim3(256), 0, stream,
                         part, mpart, sacc, macc, spacc);
    } else {
      hipMemsetAsync(sacc, 0, (size_t)(B*K*C + B*K + B*K*2)*sizeof(float), stream);
      hipLaunchKernelGGL(k_update, dim3(B*512), dim3(256), 0, stream,
                         x, out, sacc, macc, spacc);
    }
    hipLaunchKernelGGL(k_final, dim3(B*K), dim3(256), 0, stream,
                       sacc, macc, spacc, cs, cspat, outc, (it == ITERS-1) ? 1 : 0);
  }
}

// Round 14
// 1614.106 us; speedup vs baseline: 1.7159x; 1.5252x over previous
//
#include <hip/hip_runtime.h>
#include <math.h>

#define B 4
#define C 200
#define H 128
#define W 128
#define N 16384   // H*W
#define K 256
#define ITERS 5
#define FACT 1.25f   // COMPACTNESS / S = 10 / 8
#define NT 32        // split-K factor for the update GEMM

// workspace layout (floats)
#define OFF_A2    0
#define OFF_CS    (OFF_A2 + B*N)            // 65536
#define OFF_CSPAT (OFF_CS + B*K*C)          // 270336
#define OFF_B2    (OFF_CSPAT + B*K*2)       // 272384
#define OFF_SACC  (OFF_B2 + B*K)            // 273408
#define OFF_MACC  (OFF_SACC + B*K*C)        // 478208
#define OFF_SPACC (OFF_MACC + B*K)          // 479232
#define OFF_CST   (OFF_SPACC + B*K*2)       // 481280  transposed centers [B][C][K]
#define CST_SZ    (B*C*K)                   // 204800
#define OFF_PART  (OFF_CST + CST_SZ)        // 686080
#define PART_SZ   (B*NT*8*25*K)             // 6,553,600 floats (26.2 MB)
#define OFF_MPART (OFF_PART + PART_SZ)
#define MPART_SZ  (B*NT*3*K)                // 98,304 floats
#define WS_NEED   ((size_t)(OFF_MPART + MPART_SZ) * 4)

// ---------------------------------------------------------------------------
// init: centers_spectral[b,k,c] = x[0,c,seed_n(k)]; also transposed cs_t
__global__ void k_init(const float* __restrict__ x, float* __restrict__ cs,
                       float* __restrict__ cst, float* __restrict__ cspat) {
  int k = blockIdx.x, c = threadIdx.x;
  int i = k >> 4, j = k & 15;
  int sn = (4 + 8*i)*W + (4 + 8*j);
  if (c < C) {
    float v = x[(size_t)c*N + sn];
    for (int b = 0; b < B; ++b) {
      cs[((size_t)(b*K + k))*C + c] = v;
      cst[((size_t)(b*C + c))*K + k] = v;
    }
  }
  if (c == 0) {
    for (int b = 0; b < B; ++b) {
      cspat[(b*K + k)*2 + 0] = (float)(4 + 8*i);
      cspat[(b*K + k)*2 + 1] = (float)(4 + 8*j);
    }
  }
}

// a2[b,n] = sum_c x[b,c,n]^2  (iteration-invariant)
__global__ void k_a2(const float* __restrict__ x, float* __restrict__ a2) {
  int b = blockIdx.x >> 6;
  int n = ((blockIdx.x & 63) << 8) + threadIdx.x;
  const float* xp = x + (size_t)b*C*N + n;
  float s = 0.f;
  #pragma unroll 8
  for (int c = 0; c < C; ++c) { float v = xp[(size_t)c*N]; s += v*v; }
  a2[b*N + n] = s;
}

// b2[b,k] = sum_c cs[b,k,c]^2
__global__ void k_b2(const float* __restrict__ cs, float* __restrict__ b2) {
  int bk = blockIdx.x;
  const float* p = cs + (size_t)bk*C;
  float s = 0.f;
  for (int c = threadIdx.x; c < C; c += 64) { float v = p[c]; s += v*v; }
  for (int off = 32; off > 0; off >>= 1) s += __shfl_down(s, off);
  if (threadIdx.x == 0) b2[bk] = s;
}

// ---------------------------------------------------------------------------
// assignment v9: register-tiled GEMM. 512 thr; thread computes 8k x 4px
// (acc[32]); per c-step: 2 b128 cs reads (16-lane broadcast, disjoint banks)
// + 1 b128 x read + 32 FMA -> VALU-bound. cs staged [c][k] from cs_t via
// linear float4 copy (conflict-free); x staged [c][64] (conflict-free).
// launch_bounds(512,2): proven VGPR-128/no-spill config (R13).
__global__ __launch_bounds__(512, 2) void k_assign(
    const float* __restrict__ x, const float* __restrict__ cst,
    const float* __restrict__ cspat, const float* __restrict__ b2,
    const float* __restrict__ a2, float* __restrict__ Q) {
  __shared__ float cs_lds[40*K];    // 40960 B [c][k]
  __shared__ float x_lds[40*64];    // 10240 B [c][p]
  __shared__ float b2s[K], cys[K], cxs[K];  // 3072 B
  __shared__ float redp[32*65];     // 8320 B (pad 65 -> ~2-way writes)
  __shared__ float redf[64];        // 256 B

  int b   = blockIdx.x >> 8;          // 256 blocks per batch
  int n0  = (blockIdx.x & 255) << 6;  // 64 pixels per block
  int tid = threadIdx.x;
  int kgi = tid >> 4;                 // 0..31 k-group
  int k0  = kgi << 3;                 // 8 k per thread
  int p0  = (tid & 15) << 2;          // 4 px per thread

  if (tid < K) {
    b2s[tid] = b2[b*K + tid];
    cys[tid] = cspat[(b*K + tid)*2 + 0];
    cxs[tid] = cspat[(b*K + tid)*2 + 1];
  }

  float acc[32];   // [kk][pp]
  #pragma unroll
  for (int i = 0; i < 32; ++i) acc[i] = 0.f;

  const float* xb = x + (size_t)b*C*N;
  const float* ct = cst + (size_t)b*C*K;
  float4* cs4 = (float4*)cs_lds;

  for (int t = 0; t < 5; ++t) {
    int cc0 = t * 40;
    __syncthreads();   // previous tile's readers done (covers b2s init too)
    #pragma unroll
    for (int pass = 0; pass < 5; ++pass) {   // cs_t tile: linear copy 2560 f4
      int f = pass*512 + tid;
      cs4[f] = *(const float4*)&ct[(size_t)cc0*K + f*4];
    }
    #pragma unroll
    for (int pass = 0; pass < 5; ++pass) {   // x tile [40c][64p], stride-1
      int idx = pass*512 + tid;
      int ci = idx >> 6, p = idx & 63;
      x_lds[ci*64 + p] = xb[(size_t)(cc0 + ci)*N + n0 + p];
    }
    __syncthreads();
    #pragma unroll 4
    for (int c = 0; c < 40; ++c) {
      float4 cv0 = *(const float4*)&cs_lds[c*256 + k0];
      float4 cv1 = *(const float4*)&cs_lds[c*256 + k0 + 4];
      float4 xv  = *(const float4*)&x_lds[c*64 + p0];
      float cr[8] = {cv0.x, cv0.y, cv0.z, cv0.w, cv1.x, cv1.y, cv1.z, cv1.w};
      float xr[4] = {xv.x, xv.y, xv.z, xv.w};
      #pragma unroll
      for (int kk = 0; kk < 8; ++kk)
        #pragma unroll
        for (int pp = 0; pp < 4; ++pp)
          acc[kk*4 + pp] = fmaf(cr[kk], xr[pp], acc[kk*4 + pp]);
    }
  }

  // ---- distances ----
  float py  = (float)(n0 >> 7);          // all 64 px share one image row
  float pxb = (float)(n0 & 127);
  float a2v[4], mn[4];
  #pragma unroll
  for (int pp = 0; pp < 4; ++pp) {
    a2v[pp] = a2[b*N + n0 + p0 + pp];
    mn[pp] = 1e30f;
  }
  #pragma unroll
  for (int kk = 0; kk < 8; ++kk) {
    int k = k0 + kk;
    float b2v = b2s[k], cy = cys[k], cx = cxs[k];
    float dy = py - cy, dyy = dy*dy;
    #pragma unroll
    for (int pp = 0; pp < 4; ++pp) {
      float dx = pxb + (float)(p0 + pp) - cx;
      float d = sqrtf(fmaxf(a2v[pp] + b2v - 2.f*acc[kk*4+pp], 1e-12f))
              + FACT*sqrtf(fmaxf(dyy + dx*dx, 1e-12f));
      acc[kk*4+pp] = d;
      mn[pp] = fminf(mn[pp], d);
    }
  }
  // ---- softmax over K: two-stage LDS reduce across 32 k-groups ----
  #pragma unroll
  for (int pp = 0; pp < 4; ++pp) redp[kgi*65 + p0 + pp] = mn[pp];
  __syncthreads();
  if (tid < 64) {
    float m = redp[tid];
    #pragma unroll
    for (int g = 1; g < 32; ++g) m = fminf(m, redp[g*65 + tid]);
    redf[tid] = m;
  }
  __syncthreads();
  #pragma unroll
  for (int pp = 0; pp < 4; ++pp) mn[pp] = redf[p0 + pp];
  float sm[4] = {0.f, 0.f, 0.f, 0.f};
  #pragma unroll
  for (int kk = 0; kk < 8; ++kk)
    #pragma unroll
    for (int pp = 0; pp < 4; ++pp) {
      float e = __expf(mn[pp] - acc[kk*4+pp]);
      acc[kk*4+pp] = e;
      sm[pp] += e;
    }
  __syncthreads();   // min-phase redp/redf reads done before overwrite
  #pragma unroll
  for (int pp = 0; pp < 4; ++pp) redp[kgi*65 + p0 + pp] = sm[pp];
  __syncthreads();
  if (tid < 64) {
    float s = redp[tid];
    #pragma unroll
    for (int g = 1; g < 32; ++g) s += redp[g*65 + tid];
    redf[tid] = 1.f / s;
  }
  __syncthreads();
  #pragma unroll
  for (int pp = 0; pp < 4; ++pp) {
    float inv = redf[p0 + pp];
    float* qp = Q + ((size_t)(b*N + n0 + p0 + pp))*K + k0;
    float4 v0 = make_float4(acc[0*4+pp]*inv, acc[1*4+pp]*inv,
                            acc[2*4+pp]*inv, acc[3*4+pp]*inv);
    float4 v1 = make_float4(acc[4*4+pp]*inv, acc[5*4+pp]*inv,
                            acc[6*4+pp]*inv, acc[7*4+pp]*inv);
    *(float4*)&qp[0] = v0;
    *(float4*)&qp[4] = v1;
  }
}

// ---------------------------------------------------------------------------
// update v4 stage 1 (split-K, NO atomics): thread owns k=tid, 25 c's.
__global__ __launch_bounds__(256) void k_update2(
    const float* __restrict__ x, const float* __restrict__ Q,
    float* __restrict__ part, float* __restrict__ mpart) {
  __shared__ float x_lds[32*28];    // [n][c] 25 used, pad 28
  int bid = blockIdx.x;             // B*8*NT = 1024
  int b  = bid >> 8;
  int ct = (bid >> 5) & 7;          // 0..7
  int nt = bid & 31;                // 0..31
  int tid = threadIdx.x;
  int c0 = ct * 25;

  float acc[25];
  #pragma unroll
  for (int c = 0; c < 25; ++c) acc[c] = 0.f;
  float mass = 0.f, sy = 0.f, sx = 0.f;

  const float* xb = x + (size_t)b*C*N + (size_t)c0*N;
  const float* Qb = Q + (size_t)b*N*K;

  for (int ch = 0; ch < 16; ++ch) {
    int nb = nt*512 + ch*32;
    __syncthreads();
    #pragma unroll
    for (int pass = 0; pass < 4; ++pass) {  // stage x [25c][32n] -> [n][c]
      int idx = pass*256 + tid;
      if (idx < 800) {
        int ci = idx >> 5, nn = idx & 31;
        x_lds[nn*28 + ci] = xb[(size_t)ci*N + nb + nn];
      }
    }
    __syncthreads();
    float py  = (float)(nb >> 7);        // 32-n chunk stays in one image row
    float pxb = (float)(nb & 127);
    #pragma unroll
    for (int n4 = 0; n4 < 8; ++n4) {
      float qv[4];
      #pragma unroll
      for (int j = 0; j < 4; ++j)        // independent coalesced loads
        qv[j] = Qb[(size_t)(nb + n4*4 + j)*K + tid];
      #pragma unroll
      for (int j = 0; j < 4; ++j) {
        int nn = n4*4 + j;
        float q = qv[j];
        if (ct == 0) {
          mass += q;
          sy += q * py;
          sx += q * (pxb + (float)nn);
        }
        const float* xr = &x_lds[nn*28];   // wave-uniform -> broadcast
        #pragma unroll
        for (int c4 = 0; c4 < 6; ++c4) {
          float4 xv = *(const float4*)&xr[c4*4];
          acc[c4*4+0] = fmaf(q, xv.x, acc[c4*4+0]);
          acc[c4*4+1] = fmaf(q, xv.y, acc[c4*4+1]);
          acc[c4*4+2] = fmaf(q, xv.z, acc[c4*4+2]);
          acc[c4*4+3] = fmaf(q, xv.w, acc[c4*4+3]);
        }
        acc[24] = fmaf(q, xr[24], acc[24]);
      }
    }
  }
  // plain coalesced stores, no atomics
  float* pp = part + ((size_t)((b*NT + nt)*8 + ct) * 25) * K;
  #pragma unroll
  for (int c = 0; c < 25; ++c) pp[c*K + tid] = acc[c];
  if (ct == 0) {
    float* mp = mpart + (size_t)(b*NT + nt) * 3 * K;
    mp[tid]       = mass;
    mp[K + tid]   = sy;
    mp[2*K + tid] = sx;
  }
}

// update v4 stage 2: reduce NT partials per output element. grid = B*8*25.
__global__ __launch_bounds__(256) void k_reduce(
    const float* __restrict__ part, const float* __restrict__ mpart,
    float* __restrict__ sacc, float* __restrict__ macc,
    float* __restrict__ spacc) {
  int bid = blockIdx.x;        // B * 200
  int b = bid / 200;
  int r = bid % 200;
  int ct = r / 25, c = r % 25;
  int tid = threadIdx.x;
  float s = 0.f;
  for (int nt = 0; nt < NT; ++nt)
    s += part[((size_t)((b*NT + nt)*8 + ct) * 25 + c) * K + tid];
  sacc[(size_t)(b*K + tid)*C + ct*25 + c] = s;
  if (ct == 0 && c == 0) {
    float m = 0.f, yy = 0.f, xx = 0.f;
    for (int nt = 0; nt < NT; ++nt) {
      const float* mp = mpart + (size_t)(b*NT + nt) * 3 * K;
      m  += mp[tid];
      yy += mp[K + tid];
      xx += mp[2*K + tid];
    }
    macc[b*K + tid] = m;
    spacc[(b*K + tid)*2 + 0] = yy;
    spacc[(b*K + tid)*2 + 1] = xx;
  }
}

// ---------------------------------------------------------------------------
// fallback update (atomic version, used only if ws too small for partials)
__global__ __launch_bounds__(256, 2) void k_update(
    const float* __restrict__ x, const float* __restrict__ Q,
    float* __restrict__ sacc, float* __restrict__ macc,
    float* __restrict__ spacc) {
  __shared__ float x_lds[32*28];
  int bid = blockIdx.x;
  int b = bid >> 9;
  int rest = bid & 511;
  int ct = rest >> 6;
  int nt = rest & 63;
  int tid = threadIdx.x;
  int c0 = ct * 25;

  float acc[25];
  #pragma unroll
  for (int c = 0; c < 25; ++c) acc[c] = 0.f;
  float mass = 0.f, sy = 0.f, sx = 0.f;

  const float* xb = x + (size_t)b*C*N + (size_t)c0*N;
  const float* Qb = Q + (size_t)b*N*K;

  for (int ch = 0; ch < 8; ++ch) {
    int nb = nt*256 + ch*32;
    __syncthreads();
    #pragma unroll
    for (int pass = 0; pass < 4; ++pass) {
      int idx = pass*256 + tid;
      if (idx < 800) {
        int ci = idx >> 5, nn = idx & 31;
        x_lds[nn*28 + ci] = xb[(size_t)ci*N + nb + nn];
      }
    }
    __syncthreads();
    float py  = (float)(nb >> 7);
    float pxb = (float)(nb & 127);
    #pragma unroll
    for (int n4 = 0; n4 < 8; ++n4) {
      float qv[4];
      #pragma unroll
      for (int j = 0; j < 4; ++j)
        qv[j] = Qb[(size_t)(nb + n4*4 + j)*K + tid];
      #pragma unroll
      for (int j = 0; j < 4; ++j) {
        int nn = n4*4 + j;
        float q = qv[j];
        if (ct == 0) {
          mass += q;
          sy += q * py;
          sx += q * (pxb + (float)nn);
        }
        const float* xr = &x_lds[nn*28];
        #pragma unroll
        for (int c4 = 0; c4 < 6; ++c4) {
          float4 xv = *(const float4*)&xr[c4*4];
          acc[c4*4+0] = fmaf(q, xv.x, acc[c4*4+0]);
          acc[c4*4+1] = fmaf(q, xv.y, acc[c4*4+1]);
          acc[c4*4+2] = fmaf(q, xv.z, acc[c4*4+2]);
          acc[c4*4+3] = fmaf(q, xv.w, acc[c4*4+3]);
        }
        acc[24] = fmaf(q, xr[24], acc[24]);
      }
    }
  }
  float* sp = sacc + ((size_t)(b*K + tid))*C + c0;
  #pragma unroll
  for (int c = 0; c < 25; ++c) atomicAdd(&sp[c], acc[c]);
  if (ct == 0) {
    atomicAdd(&macc[b*K + tid], mass);
    atomicAdd(&spacc[(b*K + tid)*2 + 0], sy);
    atomicAdd(&spacc[(b*K + tid)*2 + 1], sx);
  }
}

// finalize: divide by mass; write centers (row-major + transposed) and d_out
__global__ void k_final(const float* __restrict__ sacc, const float* __restrict__ macc,
                        const float* __restrict__ spacc, float* __restrict__ cs,
                        float* __restrict__ cst, float* __restrict__ cspat,
                        float* __restrict__ outc, int last) {
  int bk = blockIdx.x;
  int b = bk >> 8, kk = bk & 255;
  int c = threadIdx.x;
  float inv = 1.f / (macc[bk] + 1e-6f);
  if (c < C) {
    float v = sacc[(size_t)bk*C + c] * inv;
    cs[(size_t)bk*C + c] = v;
    cst[((size_t)(b*C + c))*K + kk] = v;
    if (last) outc[(size_t)bk*C + c] = v;
  } else if (c == C) {
    cspat[bk*2 + 0] = spacc[bk*2 + 0] * inv;
  } else if (c == C + 1) {
    cspat[bk*2 + 1] = spacc[bk*2 + 1] * inv;
  }
}

extern "C" void kernel_launch(void* const* d_in, const int* in_sizes, int n_in,
                              void* d_out, int out_size, void* d_ws, size_t ws_size,
                              hipStream_t stream) {
  const float* x = (const float*)d_in[0];
  float* out = (float*)d_out;
  float* ws  = (float*)d_ws;
  float* a2    = ws + OFF_A2;
  float* cs    = ws + OFF_CS;
  float* cspat = ws + OFF_CSPAT;
  float* b2    = ws + OFF_B2;
  float* sacc  = ws + OFF_SACC;
  float* macc  = ws + OFF_MACC;
  float* spacc = ws + OFF_SPACC;
  float* cst   = ws + OFF_CST;
  float* part  = ws + OFF_PART;
  float* mpart = ws + OFF_MPART;
  float* outc  = out + (size_t)B*N*K;
  int split = (ws_size >= WS_NEED) ? 1 : 0;

  hipLaunchKernelGGL(k_init, dim3(K), dim3(256), 0, stream, x, cs, cst, cspat);
  hipLaunchKernelGGL(k_a2, dim3(B*64), dim3(256), 0, stream, x, a2);
  for (int it = 0; it < ITERS; ++it) {
    hipLaunchKernelGGL(k_b2, dim3(B*K), dim3(64), 0, stream, cs, b2);
    hipLaunchKernelGGL(k_assign, dim3(B*256), dim3(512), 0, stream,
                       x, cst, cspat, b2, a2, out);
    if (split) {
      hipLaunchKernelGGL(k_update2, dim3(B*8*NT), dim3(256), 0, stream,
                         x, out, part, mpart);
      hipLaunchKernelGGL(k_reduce, dim3(B*200), dim3(256), 0, stream,
                         part, mpart, sacc, macc, spacc);
    } else {
      hipMemsetAsync(sacc, 0, (size_t)(B*K*C + B*K + B*K*2)*sizeof(float), stream);
      hipLaunchKernelGGL(k_update, dim3(B*512), dim3(256), 0, stream,
                         x, out, sacc, macc, spacc);
    }
    hipLaunchKernelGGL(k_final, dim3(B*K), dim3(256), 0, stream,
                       sacc, macc, spacc, cs, cst, cspat, outc,
                       (it == ITERS-1) ? 1 : 0);
  }
}

// Round 15
// 1341.782 us; speedup vs baseline: 2.0641x; 1.2030x over previous
//
#include <hip/hip_runtime.h>
#include <math.h>

#define B 4
#define C 200
#define H 128
#define W 128
#define N 16384   // H*W
#define K 256
#define ITERS 5
#define FACT 1.25f   // COMPACTNESS / S = 10 / 8
#define NT 32        // split-K n-tiles for the update GEMM (512 n each)
#define NTM 128      // n-tiles for k_mass (128 n each)

// workspace layout (floats)
#define OFF_A2    0
#define OFF_CS    (OFF_A2 + B*N)            // 65536
#define OFF_CSPAT (OFF_CS + B*K*C)          // 270336
#define OFF_B2    (OFF_CSPAT + B*K*2)       // 272384
#define OFF_SACC  (OFF_B2 + B*K)            // 273408
#define OFF_MACC  (OFF_SACC + B*K*C)        // 478208
#define OFF_SPACC (OFF_MACC + B*K)          // 479232
#define OFF_CST   (OFF_SPACC + B*K*2)       // 481280  transposed centers [B][C][K]
#define CST_SZ    (B*C*K)                   // 204800
#define OFF_PART  (OFF_CST + CST_SZ)        // 686080
#define PART_SZ   (B*NT*5*40*K)             // 6,553,600 floats (26.2 MB)
#define OFF_MPART (OFF_PART + PART_SZ)
#define MPART_SZ  (B*NTM*3*K)               // 393,216 floats
#define WS_NEED   ((size_t)(OFF_MPART + MPART_SZ) * 4)

// ---------------------------------------------------------------------------
// init: centers_spectral[b,k,c] = x[0,c,seed_n(k)]; also transposed cs_t
__global__ void k_init(const float* __restrict__ x, float* __restrict__ cs,
                       float* __restrict__ cst, float* __restrict__ cspat) {
  int k = blockIdx.x, c = threadIdx.x;
  int i = k >> 4, j = k & 15;
  int sn = (4 + 8*i)*W + (4 + 8*j);
  if (c < C) {
    float v = x[(size_t)c*N + sn];
    for (int b = 0; b < B; ++b) {
      cs[((size_t)(b*K + k))*C + c] = v;
      cst[((size_t)(b*C + c))*K + k] = v;
    }
  }
  if (c == 0) {
    for (int b = 0; b < B; ++b) {
      cspat[(b*K + k)*2 + 0] = (float)(4 + 8*i);
      cspat[(b*K + k)*2 + 1] = (float)(4 + 8*j);
    }
  }
}

// a2[b,n] = sum_c x[b,c,n]^2  (iteration-invariant)
__global__ void k_a2(const float* __restrict__ x, float* __restrict__ a2) {
  int b = blockIdx.x >> 6;
  int n = ((blockIdx.x & 63) << 8) + threadIdx.x;
  const float* xp = x + (size_t)b*C*N + n;
  float s = 0.f;
  #pragma unroll 8
  for (int c = 0; c < C; ++c) { float v = xp[(size_t)c*N]; s += v*v; }
  a2[b*N + n] = s;
}

// b2[b,k] = sum_c cs[b,k,c]^2
__global__ void k_b2(const float* __restrict__ cs, float* __restrict__ b2) {
  int bk = blockIdx.x;
  const float* p = cs + (size_t)bk*C;
  float s = 0.f;
  for (int c = threadIdx.x; c < C; c += 64) { float v = p[c]; s += v*v; }
  for (int off = 32; off > 0; off >>= 1) s += __shfl_down(s, off);
  if (threadIdx.x == 0) b2[bk] = s;
}

// ---------------------------------------------------------------------------
// assignment v9 (unchanged from R14): register-tiled GEMM, 8k x 4px/thread.
__global__ __launch_bounds__(512, 2) void k_assign(
    const float* __restrict__ x, const float* __restrict__ cst,
    const float* __restrict__ cspat, const float* __restrict__ b2,
    const float* __restrict__ a2, float* __restrict__ Q) {
  __shared__ float cs_lds[40*K];    // 40960 B [c][k]
  __shared__ float x_lds[40*64];    // 10240 B [c][p]
  __shared__ float b2s[K], cys[K], cxs[K];  // 3072 B
  __shared__ float redp[32*65];     // 8320 B (pad 65)
  __shared__ float redf[64];        // 256 B

  int b   = blockIdx.x >> 8;          // 256 blocks per batch
  int n0  = (blockIdx.x & 255) << 6;  // 64 pixels per block
  int tid = threadIdx.x;
  int kgi = tid >> 4;                 // 0..31 k-group
  int k0  = kgi << 3;                 // 8 k per thread
  int p0  = (tid & 15) << 2;          // 4 px per thread

  if (tid < K) {
    b2s[tid] = b2[b*K + tid];
    cys[tid] = cspat[(b*K + tid)*2 + 0];
    cxs[tid] = cspat[(b*K + tid)*2 + 1];
  }

  float acc[32];   // [kk][pp]
  #pragma unroll
  for (int i = 0; i < 32; ++i) acc[i] = 0.f;

  const float* xb = x + (size_t)b*C*N;
  const float* ct = cst + (size_t)b*C*K;
  float4* cs4 = (float4*)cs_lds;

  for (int t = 0; t < 5; ++t) {
    int cc0 = t * 40;
    __syncthreads();
    #pragma unroll
    for (int pass = 0; pass < 5; ++pass) {   // cs_t tile: linear copy 2560 f4
      int f = pass*512 + tid;
      cs4[f] = *(const float4*)&ct[(size_t)cc0*K + f*4];
    }
    #pragma unroll
    for (int pass = 0; pass < 5; ++pass) {   // x tile [40c][64p], stride-1
      int idx = pass*512 + tid;
      int ci = idx >> 6, p = idx & 63;
      x_lds[ci*64 + p] = xb[(size_t)(cc0 + ci)*N + n0 + p];
    }
    __syncthreads();
    #pragma unroll 4
    for (int c = 0; c < 40; ++c) {
      float4 cv0 = *(const float4*)&cs_lds[c*256 + k0];
      float4 cv1 = *(const float4*)&cs_lds[c*256 + k0 + 4];
      float4 xv  = *(const float4*)&x_lds[c*64 + p0];
      float cr[8] = {cv0.x, cv0.y, cv0.z, cv0.w, cv1.x, cv1.y, cv1.z, cv1.w};
      float xr[4] = {xv.x, xv.y, xv.z, xv.w};
      #pragma unroll
      for (int kk = 0; kk < 8; ++kk)
        #pragma unroll
        for (int pp = 0; pp < 4; ++pp)
          acc[kk*4 + pp] = fmaf(cr[kk], xr[pp], acc[kk*4 + pp]);
    }
  }

  float py  = (float)(n0 >> 7);
  float pxb = (float)(n0 & 127);
  float a2v[4], mn[4];
  #pragma unroll
  for (int pp = 0; pp < 4; ++pp) {
    a2v[pp] = a2[b*N + n0 + p0 + pp];
    mn[pp] = 1e30f;
  }
  #pragma unroll
  for (int kk = 0; kk < 8; ++kk) {
    int k = k0 + kk;
    float b2v = b2s[k], cy = cys[k], cx = cxs[k];
    float dy = py - cy, dyy = dy*dy;
    #pragma unroll
    for (int pp = 0; pp < 4; ++pp) {
      float dx = pxb + (float)(p0 + pp) - cx;
      float d = sqrtf(fmaxf(a2v[pp] + b2v - 2.f*acc[kk*4+pp], 1e-12f))
              + FACT*sqrtf(fmaxf(dyy + dx*dx, 1e-12f));
      acc[kk*4+pp] = d;
      mn[pp] = fminf(mn[pp], d);
    }
  }
  #pragma unroll
  for (int pp = 0; pp < 4; ++pp) redp[kgi*65 + p0 + pp] = mn[pp];
  __syncthreads();
  if (tid < 64) {
    float m = redp[tid];
    #pragma unroll
    for (int g = 1; g < 32; ++g) m = fminf(m, redp[g*65 + tid]);
    redf[tid] = m;
  }
  __syncthreads();
  #pragma unroll
  for (int pp = 0; pp < 4; ++pp) mn[pp] = redf[p0 + pp];
  float sm[4] = {0.f, 0.f, 0.f, 0.f};
  #pragma unroll
  for (int kk = 0; kk < 8; ++kk)
    #pragma unroll
    for (int pp = 0; pp < 4; ++pp) {
      float e = __expf(mn[pp] - acc[kk*4+pp]);
      acc[kk*4+pp] = e;
      sm[pp] += e;
    }
  __syncthreads();
  #pragma unroll
  for (int pp = 0; pp < 4; ++pp) redp[kgi*65 + p0 + pp] = sm[pp];
  __syncthreads();
  if (tid < 64) {
    float s = redp[tid];
    #pragma unroll
    for (int g = 1; g < 32; ++g) s += redp[g*65 + tid];
    redf[tid] = 1.f / s;
  }
  __syncthreads();
  #pragma unroll
  for (int pp = 0; pp < 4; ++pp) {
    float inv = redf[p0 + pp];
    float* qp = Q + ((size_t)(b*N + n0 + p0 + pp))*K + k0;
    float4 v0 = make_float4(acc[0*4+pp]*inv, acc[1*4+pp]*inv,
                            acc[2*4+pp]*inv, acc[3*4+pp]*inv);
    float4 v1 = make_float4(acc[4*4+pp]*inv, acc[5*4+pp]*inv,
                            acc[6*4+pp]*inv, acc[7*4+pp]*inv);
    *(float4*)&qp[0] = v0;
    *(float4*)&qp[4] = v1;
  }
}

// ---------------------------------------------------------------------------
// update v5 stage 1: register-tiled GEMM, 4k x 10c per thread, no atomics.
// 256 thr = 64 kgroups(4k) x 4 cgroups(10c). Block = 256k x 40c x 512n.
// Q staged [32n][256k] (linear f4, conflict-free); x staged [40c][34n]
// (pad34 -> 2-way=free; even-n float2 reads aligned). Per 2-n: 2 Q b128 +
// 10 x b64 broadcasts (~84 cyc) vs 80 FMA (160 cyc) -> VALU-bound.
__global__ __launch_bounds__(256) void k_update3(
    const float* __restrict__ x, const float* __restrict__ Q,
    float* __restrict__ part) {
  __shared__ float q_lds[32*256];   // 32 KB [n][k]
  __shared__ float x_lds[40*34];    // 5.4 KB [c][n] pad 34
  int bid = blockIdx.x;             // B*5*NT = 640
  int b   = bid / 160;
  int rem = bid - b*160;
  int ct  = rem >> 5;               // 0..4
  int nt  = rem & 31;               // 0..31
  int tid = threadIdx.x;
  int kg  = tid & 63;               // 64 kgroups
  int k0  = kg << 2;                // 4 k per thread
  int cg  = tid >> 6;               // 4 cgroups
  int cbase = cg * 10;              // 10 c per thread
  int c0  = ct * 40;

  float acc[40];                    // [kk][c] = acc[kk*10 + c]
  #pragma unroll
  for (int i = 0; i < 40; ++i) acc[i] = 0.f;

  const float* xb = x + (size_t)b*C*N + (size_t)c0*N;
  const float4* Q4 = (const float4*)(Q + (size_t)b*N*K);
  float4* q4 = (float4*)q_lds;

  for (int ch = 0; ch < 16; ++ch) {
    int nb = nt*512 + ch*32;
    __syncthreads();
    #pragma unroll
    for (int pass = 0; pass < 8; ++pass) {   // Q tile: 2048 f4, linear
      int idx = pass*256 + tid;
      q4[idx] = Q4[(size_t)(nb + (idx >> 6))*64 + (idx & 63)];
    }
    #pragma unroll
    for (int pass = 0; pass < 5; ++pass) {   // x tile [40c][34n]
      int idx = pass*256 + tid;
      int ci = idx >> 5, nn = idx & 31;
      x_lds[ci*34 + nn] = xb[(size_t)ci*N + nb + nn];
    }
    __syncthreads();
    #pragma unroll 4
    for (int nn = 0; nn < 32; nn += 2) {
      float4 qv0 = *(const float4*)&q_lds[nn*256 + k0];
      float4 qv1 = *(const float4*)&q_lds[(nn+1)*256 + k0];
      float qr0[4] = {qv0.x, qv0.y, qv0.z, qv0.w};
      float qr1[4] = {qv1.x, qv1.y, qv1.z, qv1.w};
      #pragma unroll
      for (int c = 0; c < 10; ++c) {
        float2 xv = *(const float2*)&x_lds[(cbase + c)*34 + nn]; // broadcast
        #pragma unroll
        for (int kk = 0; kk < 4; ++kk) {
          float a = acc[kk*10 + c];
          a = fmaf(qr0[kk], xv.x, a);
          a = fmaf(qr1[kk], xv.y, a);
          acc[kk*10 + c] = a;
        }
      }
    }
  }
  // coalesced f4 partial stores (consecutive kg -> consecutive 16B)
  float* pp = part + ((size_t)((b*NT + nt)*5 + ct) * 40) * K;
  #pragma unroll
  for (int c = 0; c < 10; ++c) {
    float4 v = make_float4(acc[0*10+c], acc[1*10+c], acc[2*10+c], acc[3*10+c]);
    *(float4*)&pp[(size_t)(cbase + c)*K + k0] = v;
  }
}

// mass/spatial sums: mass[k] = sum_n Q[n][k], etc. grid = B*NTM, 128 n each.
__global__ __launch_bounds__(256) void k_mass(
    const float* __restrict__ Q, float* __restrict__ mpart) {
  int bid = blockIdx.x;             // B*NTM = 512
  int b = bid >> 7, nt = bid & 127;
  int tid = threadIdx.x;
  const float* Qb = Q + (size_t)b*N*K;
  int nbase = nt * 128;
  float mass = 0.f, sy = 0.f, sx = 0.f;
  for (int nn = 0; nn < 128; nn += 8) {
    float qv[8];
    #pragma unroll
    for (int j = 0; j < 8; ++j)
      qv[j] = Qb[(size_t)(nbase + nn + j)*K + tid];
    #pragma unroll
    for (int j = 0; j < 8; ++j) {
      int n = nbase + nn + j;
      mass += qv[j];
      sy += qv[j] * (float)(n >> 7);
      sx += qv[j] * (float)(n & 127);
    }
  }
  float* mp = mpart + (size_t)(b*NTM + nt) * 3 * K;
  mp[tid]       = mass;
  mp[K + tid]   = sy;
  mp[2*K + tid] = sx;
}

// stage 2: reduce NT partials per output element. grid = B*200.
__global__ __launch_bounds__(256) void k_reduce(
    const float* __restrict__ part, const float* __restrict__ mpart,
    float* __restrict__ sacc, float* __restrict__ macc,
    float* __restrict__ spacc) {
  int bid = blockIdx.x;        // B * 200
  int b = bid / 200;
  int r = bid % 200;
  int ct = r / 40, cw = r % 40;
  int tid = threadIdx.x;
  float s = 0.f;
  for (int nt = 0; nt < NT; ++nt)
    s += part[(((size_t)(b*NT + nt)*5 + ct)*40 + cw)*K + tid];
  sacc[(size_t)(b*K + tid)*C + ct*40 + cw] = s;
  if (r == 0) {
    float m = 0.f, yy = 0.f, xx = 0.f;
    for (int nt = 0; nt < NTM; ++nt) {
      const float* mp = mpart + (size_t)(b*NTM + nt) * 3 * K;
      m  += mp[tid];
      yy += mp[K + tid];
      xx += mp[2*K + tid];
    }
    macc[b*K + tid] = m;
    spacc[(b*K + tid)*2 + 0] = yy;
    spacc[(b*K + tid)*2 + 1] = xx;
  }
}

// ---------------------------------------------------------------------------
// fallback update (atomic version, used only if ws too small for partials)
__global__ __launch_bounds__(256, 2) void k_update(
    const float* __restrict__ x, const float* __restrict__ Q,
    float* __restrict__ sacc, float* __restrict__ macc,
    float* __restrict__ spacc) {
  __shared__ float x_lds[32*28];
  int bid = blockIdx.x;
  int b = bid >> 9;
  int rest = bid & 511;
  int ct = rest >> 6;
  int nt = rest & 63;
  int tid = threadIdx.x;
  int c0 = ct * 25;

  float acc[25];
  #pragma unroll
  for (int c = 0; c < 25; ++c) acc[c] = 0.f;
  float mass = 0.f, sy = 0.f, sx = 0.f;

  const float* xb = x + (size_t)b*C*N + (size_t)c0*N;
  const float* Qb = Q + (size_t)b*N*K;

  for (int ch = 0; ch < 8; ++ch) {
    int nb = nt*256 + ch*32;
    __syncthreads();
    #pragma unroll
    for (int pass = 0; pass < 4; ++pass) {
      int idx = pass*256 + tid;
      if (idx < 800) {
        int ci = idx >> 5, nn = idx & 31;
        x_lds[nn*28 + ci] = xb[(size_t)ci*N + nb + nn];
      }
    }
    __syncthreads();
    float py  = (float)(nb >> 7);
    float pxb = (float)(nb & 127);
    #pragma unroll
    for (int n4 = 0; n4 < 8; ++n4) {
      float qv[4];
      #pragma unroll
      for (int j = 0; j < 4; ++j)
        qv[j] = Qb[(size_t)(nb + n4*4 + j)*K + tid];
      #pragma unroll
      for (int j = 0; j < 4; ++j) {
        int nn = n4*4 + j;
        float q = qv[j];
        if (ct == 0) {
          mass += q;
          sy += q * py;
          sx += q * (pxb + (float)nn);
        }
        const float* xr = &x_lds[nn*28];
        #pragma unroll
        for (int c4 = 0; c4 < 6; ++c4) {
          float4 xv = *(const float4*)&xr[c4*4];
          acc[c4*4+0] = fmaf(q, xv.x, acc[c4*4+0]);
          acc[c4*4+1] = fmaf(q, xv.y, acc[c4*4+1]);
          acc[c4*4+2] = fmaf(q, xv.z, acc[c4*4+2]);
          acc[c4*4+3] = fmaf(q, xv.w, acc[c4*4+3]);
        }
        acc[24] = fmaf(q, xr[24], acc[24]);
      }
    }
  }
  float* sp = sacc + ((size_t)(b*K + tid))*C + c0;
  #pragma unroll
  for (int c = 0; c < 25; ++c) atomicAdd(&sp[c], acc[c]);
  if (ct == 0) {
    atomicAdd(&macc[b*K + tid], mass);
    atomicAdd(&spacc[(b*K + tid)*2 + 0], sy);
    atomicAdd(&spacc[(b*K + tid)*2 + 1], sx);
  }
}

// finalize: divide by mass; write centers (row-major + transposed) and d_out
__global__ void k_final(const float* __restrict__ sacc, const float* __restrict__ macc,
                        const float* __restrict__ spacc, float* __restrict__ cs,
                        float* __restrict__ cst, float* __restrict__ cspat,
                        float* __restrict__ outc, int last) {
  int bk = blockIdx.x;
  int b = bk >> 8, kk = bk & 255;
  int c = threadIdx.x;
  float inv = 1.f / (macc[bk] + 1e-6f);
  if (c < C) {
    float v = sacc[(size_t)bk*C + c] * inv;
    cs[(size_t)bk*C + c] = v;
    cst[((size_t)(b*C + c))*K + kk] = v;
    if (last) outc[(size_t)bk*C + c] = v;
  } else if (c == C) {
    cspat[bk*2 + 0] = spacc[bk*2 + 0] * inv;
  } else if (c == C + 1) {
    cspat[bk*2 + 1] = spacc[bk*2 + 1] * inv;
  }
}

extern "C" void kernel_launch(void* const* d_in, const int* in_sizes, int n_in,
                              void* d_out, int out_size, void* d_ws, size_t ws_size,
                              hipStream_t stream) {
  const float* x = (const float*)d_in[0];
  float* out = (float*)d_out;
  float* ws  = (float*)d_ws;
  float* a2    = ws + OFF_A2;
  float* cs    = ws + OFF_CS;
  float* cspat = ws + OFF_CSPAT;
  float* b2    = ws + OFF_B2;
  float* sacc  = ws + OFF_SACC;
  float* macc  = ws + OFF_MACC;
  float* spacc = ws + OFF_SPACC;
  float* cst   = ws + OFF_CST;
  float* part  = ws + OFF_PART;
  float* mpart = ws + OFF_MPART;
  float* outc  = out + (size_t)B*N*K;
  int split = (ws_size >= WS_NEED) ? 1 : 0;

  hipLaunchKernelGGL(k_init, dim3(K), dim3(256), 0, stream, x, cs, cst, cspat);
  hipLaunchKernelGGL(k_a2, dim3(B*64), dim3(256), 0, stream, x, a2);
  for (int it = 0; it < ITERS; ++it) {
    hipLaunchKernelGGL(k_b2, dim3(B*K), dim3(64), 0, stream, cs, b2);
    hipLaunchKernelGGL(k_assign, dim3(B*256), dim3(512), 0, stream,
                       x, cst, cspat, b2, a2, out);
    if (split) {
      hipLaunchKernelGGL(k_update3, dim3(B*5*NT), dim3(256), 0, stream,
                         x, out, part);
      hipLaunchKernelGGL(k_mass, dim3(B*NTM), dim3(256), 0, stream,
                         out, mpart);
      hipLaunchKernelGGL(k_reduce, dim3(B*200), dim3(256), 0, stream,
                         part, mpart, sacc, macc, spacc);
    } else {
      hipMemsetAsync(sacc, 0, (size_t)(B*K*C + B*K + B*K*2)*sizeof(float), stream);
      hipLaunchKernelGGL(k_update, dim3(B*512), dim3(256), 0, stream,
                         x, out, sacc, macc, spacc);
    }
    hipLaunchKernelGGL(k_final, dim3(B*K), dim3(256), 0, stream,
                       sacc, macc, spacc, cs, cst, cspat, outc,
                       (it == ITERS-1) ? 1 : 0);
  }
}

// Round 16
// 1216.860 us; speedup vs baseline: 2.2760x; 1.1027x over previous
//
#include <hip/hip_runtime.h>
#include <math.h>

#define B 4
#define C 200
#define H 128
#define W 128
#define N 16384   // H*W
#define K 256
#define ITERS 5
#define FACT 1.25f   // COMPACTNESS / S = 10 / 8
#define NT 32        // split-K n-tiles for the update GEMM (512 n each)
#define NTM 128      // n-tiles for k_mass (128 n each)

// workspace layout (floats)
#define OFF_A2    0
#define OFF_CS    (OFF_A2 + B*N)            // 65536
#define OFF_CSPAT (OFF_CS + B*K*C)          // 270336
#define OFF_B2    (OFF_CSPAT + B*K*2)       // 272384
#define OFF_SACC  (OFF_B2 + B*K)            // 273408
#define OFF_MACC  (OFF_SACC + B*K*C)        // 478208
#define OFF_SPACC (OFF_MACC + B*K)          // 479232
#define OFF_CST   (OFF_SPACC + B*K*2)       // 481280  transposed centers [B][C][K]
#define CST_SZ    (B*C*K)                   // 204800
#define OFF_PART  (OFF_CST + CST_SZ)        // 686080
#define PART_SZ   (B*NT*5*40*K)             // 6,553,600 floats (26.2 MB)
#define OFF_MPART (OFF_PART + PART_SZ)
#define MPART_SZ  (B*NTM*3*K)               // 393,216 floats
#define WS_NEED   ((size_t)(OFF_MPART + MPART_SZ) * 4)

// ---------------------------------------------------------------------------
// init: centers_spectral[b,k,c] = x[0,c,seed_n(k)]; also transposed cs_t
__global__ void k_init(const float* __restrict__ x, float* __restrict__ cs,
                       float* __restrict__ cst, float* __restrict__ cspat) {
  int k = blockIdx.x, c = threadIdx.x;
  int i = k >> 4, j = k & 15;
  int sn = (4 + 8*i)*W + (4 + 8*j);
  if (c < C) {
    float v = x[(size_t)c*N + sn];
    for (int b = 0; b < B; ++b) {
      cs[((size_t)(b*K + k))*C + c] = v;
      cst[((size_t)(b*C + c))*K + k] = v;
    }
  }
  if (c == 0) {
    for (int b = 0; b < B; ++b) {
      cspat[(b*K + k)*2 + 0] = (float)(4 + 8*i);
      cspat[(b*K + k)*2 + 1] = (float)(4 + 8*j);
    }
  }
}

// a2[b,n] = sum_c x[b,c,n]^2  (iteration-invariant)
__global__ void k_a2(const float* __restrict__ x, float* __restrict__ a2) {
  int b = blockIdx.x >> 6;
  int n = ((blockIdx.x & 63) << 8) + threadIdx.x;
  const float* xp = x + (size_t)b*C*N + n;
  float s = 0.f;
  #pragma unroll 8
  for (int c = 0; c < C; ++c) { float v = xp[(size_t)c*N]; s += v*v; }
  a2[b*N + n] = s;
}

// b2[b,k] = sum_c cs[b,k,c]^2
__global__ void k_b2(const float* __restrict__ cs, float* __restrict__ b2) {
  int bk = blockIdx.x;
  const float* p = cs + (size_t)bk*C;
  float s = 0.f;
  for (int c = threadIdx.x; c < C; c += 64) { float v = p[c]; s += v*v; }
  for (int off = 32; off > 0; off >>= 1) s += __shfl_down(s, off);
  if (threadIdx.x == 0) b2[bk] = s;
}

// ---------------------------------------------------------------------------
// assignment v10: register-tiled GEMM, 8k x 8px per thread (acc[64]).
// 512 thr = 32 kgroups(8k) x 16 pgroups(8px); block = 256k x 128px.
// Per c-step: 2 cs b128 (4 distinct k0/wave, disjoint banks) + 2 x b128
// (4-way) feed 64 FMA -> VALU-bound ~2:1. Softmax scratch OVERLAYS x_lds
// (dead after t-loop) so LDS = 64.5KB -> 2 blocks/CU at (512,2)/128-VGPR-cap.
__global__ __launch_bounds__(512, 2) void k_assign(
    const float* __restrict__ x, const float* __restrict__ cst,
    const float* __restrict__ cspat, const float* __restrict__ b2,
    const float* __restrict__ a2, float* __restrict__ Q) {
  __shared__ float cs_lds[40*K];    // 40960 B [c][k]
  __shared__ float xr_lds[40*128];  // 20480 B [c][p]; reused as redp/redf
  __shared__ float b2s[K], cys[K], cxs[K];  // 3072 B
  float* redp = xr_lds;             // [32][136] = 4352 floats
  float* redf = xr_lds + 4352;      // [128]

  int b   = blockIdx.x >> 7;          // 128 blocks per batch
  int n0  = (blockIdx.x & 127) << 7;  // 128 pixels per block
  int tid = threadIdx.x;
  int kgi = tid >> 4;                 // 0..31
  int k0  = kgi << 3;                 // 8 k per thread
  int p0  = (tid & 15) << 3;          // 8 px per thread

  if (tid < K) {
    b2s[tid] = b2[b*K + tid];
    cys[tid] = cspat[(b*K + tid)*2 + 0];
    cxs[tid] = cspat[(b*K + tid)*2 + 1];
  }

  float acc[64];   // [kk][pp] = acc[kk*8+pp]
  #pragma unroll
  for (int i = 0; i < 64; ++i) acc[i] = 0.f;

  const float* xb = x + (size_t)b*C*N;
  const float* ct = cst + (size_t)b*C*K;
  float4* cs4 = (float4*)cs_lds;
  float4* xr4 = (float4*)xr_lds;

  for (int t = 0; t < 5; ++t) {
    int cc0 = t * 40;
    __syncthreads();
    #pragma unroll
    for (int pass = 0; pass < 5; ++pass) {   // cs_t tile: linear copy 2560 f4
      int f = pass*512 + tid;
      cs4[f] = *(const float4*)&ct[(size_t)cc0*K + f*4];
    }
    #pragma unroll
    for (int pass = 0; pass < 3; ++pass) {   // x tile [40c][128p]: 1280 f4
      int idx = pass*512 + tid;
      if (idx < 1280) {
        int ci = idx >> 5, pq = idx & 31;
        xr4[idx] = *(const float4*)&xb[(size_t)(cc0 + ci)*N + n0 + pq*4];
      }
    }
    __syncthreads();
    #pragma unroll 2
    for (int c = 0; c < 40; ++c) {
      float4 cv0 = *(const float4*)&cs_lds[c*256 + k0];
      float4 cv1 = *(const float4*)&cs_lds[c*256 + k0 + 4];
      float4 xv0 = *(const float4*)&xr_lds[c*128 + p0];
      float4 xv1 = *(const float4*)&xr_lds[c*128 + p0 + 4];
      float cr[8] = {cv0.x, cv0.y, cv0.z, cv0.w, cv1.x, cv1.y, cv1.z, cv1.w};
      float xr[8] = {xv0.x, xv0.y, xv0.z, xv0.w, xv1.x, xv1.y, xv1.z, xv1.w};
      #pragma unroll
      for (int kk = 0; kk < 8; ++kk)
        #pragma unroll
        for (int pp = 0; pp < 8; ++pp)
          acc[kk*8 + pp] = fmaf(cr[kk], xr[pp], acc[kk*8 + pp]);
    }
  }
  __syncthreads();   // all x_lds reads done before redp overlay writes

  // ---- distances ----
  float py  = (float)(n0 >> 7);          // all 128 px share one image row
  float pxb = (float)(n0 & 127);
  float a2v[8], mn[8];
  #pragma unroll
  for (int pp = 0; pp < 8; ++pp) {
    a2v[pp] = a2[b*N + n0 + p0 + pp];
    mn[pp] = 1e30f;
  }
  #pragma unroll
  for (int kk = 0; kk < 8; ++kk) {
    int k = k0 + kk;
    float b2v = b2s[k], cy = cys[k], cx = cxs[k];
    float dy = py - cy, dyy = dy*dy;
    #pragma unroll
    for (int pp = 0; pp < 8; ++pp) {
      float dx = pxb + (float)(p0 + pp) - cx;
      float d = sqrtf(fmaxf(a2v[pp] + b2v - 2.f*acc[kk*8+pp], 1e-12f))
              + FACT*sqrtf(fmaxf(dyy + dx*dx, 1e-12f));
      acc[kk*8+pp] = d;
      mn[pp] = fminf(mn[pp], d);
    }
  }
  // ---- softmax over K: two-stage reduce across 32 kgroups ----
  #pragma unroll
  for (int pp = 0; pp < 8; ++pp) redp[kgi*136 + p0 + pp] = mn[pp];
  __syncthreads();
  if (tid < 128) {
    float m = redp[tid];
    #pragma unroll
    for (int g = 1; g < 32; ++g) m = fminf(m, redp[g*136 + tid]);
    redf[tid] = m;
  }
  __syncthreads();
  #pragma unroll
  for (int pp = 0; pp < 8; ++pp) mn[pp] = redf[p0 + pp];
  float sm[8] = {0.f,0.f,0.f,0.f,0.f,0.f,0.f,0.f};
  #pragma unroll
  for (int kk = 0; kk < 8; ++kk)
    #pragma unroll
    for (int pp = 0; pp < 8; ++pp) {
      float e = __expf(mn[pp] - acc[kk*8+pp]);
      acc[kk*8+pp] = e;
      sm[pp] += e;
    }
  __syncthreads();   // redf min-reads done before sum overwrite path
  #pragma unroll
  for (int pp = 0; pp < 8; ++pp) redp[kgi*136 + p0 + pp] = sm[pp];
  __syncthreads();
  if (tid < 128) {
    float s = redp[tid];
    #pragma unroll
    for (int g = 1; g < 32; ++g) s += redp[g*136 + tid];
    redf[tid] = 1.f / s;
  }
  __syncthreads();
  #pragma unroll
  for (int pp = 0; pp < 8; ++pp) {
    float inv = redf[p0 + pp];
    float* qp = Q + ((size_t)(b*N + n0 + p0 + pp))*K + k0;
    float4 v0 = make_float4(acc[0*8+pp]*inv, acc[1*8+pp]*inv,
                            acc[2*8+pp]*inv, acc[3*8+pp]*inv);
    float4 v1 = make_float4(acc[4*8+pp]*inv, acc[5*8+pp]*inv,
                            acc[6*8+pp]*inv, acc[7*8+pp]*inv);
    *(float4*)&qp[0] = v0;
    *(float4*)&qp[4] = v1;
  }
}

// ---------------------------------------------------------------------------
// update v5 stage 1 (unchanged from R15): register-tiled 4k x 10c, no atomics.
__global__ __launch_bounds__(256) void k_update3(
    const float* __restrict__ x, const float* __restrict__ Q,
    float* __restrict__ part) {
  __shared__ float q_lds[32*256];   // 32 KB [n][k]
  __shared__ float x_lds[40*34];    // 5.4 KB [c][n] pad 34
  int bid = blockIdx.x;             // B*5*NT = 640
  int b   = bid / 160;
  int rem = bid - b*160;
  int ct  = rem >> 5;               // 0..4
  int nt  = rem & 31;               // 0..31
  int tid = threadIdx.x;
  int kg  = tid & 63;               // 64 kgroups
  int k0  = kg << 2;                // 4 k per thread
  int cg  = tid >> 6;               // 4 cgroups
  int cbase = cg * 10;              // 10 c per thread
  int c0  = ct * 40;

  float acc[40];                    // [kk][c] = acc[kk*10 + c]
  #pragma unroll
  for (int i = 0; i < 40; ++i) acc[i] = 0.f;

  const float* xb = x + (size_t)b*C*N + (size_t)c0*N;
  const float4* Q4 = (const float4*)(Q + (size_t)b*N*K);
  float4* q4 = (float4*)q_lds;

  for (int ch = 0; ch < 16; ++ch) {
    int nb = nt*512 + ch*32;
    __syncthreads();
    #pragma unroll
    for (int pass = 0; pass < 8; ++pass) {   // Q tile: 2048 f4, linear
      int idx = pass*256 + tid;
      q4[idx] = Q4[(size_t)(nb + (idx >> 6))*64 + (idx & 63)];
    }
    #pragma unroll
    for (int pass = 0; pass < 5; ++pass) {   // x tile [40c][34n]
      int idx = pass*256 + tid;
      int ci = idx >> 5, nn = idx & 31;
      x_lds[ci*34 + nn] = xb[(size_t)ci*N + nb + nn];
    }
    __syncthreads();
    #pragma unroll 4
    for (int nn = 0; nn < 32; nn += 2) {
      float4 qv0 = *(const float4*)&q_lds[nn*256 + k0];
      float4 qv1 = *(const float4*)&q_lds[(nn+1)*256 + k0];
      float qr0[4] = {qv0.x, qv0.y, qv0.z, qv0.w};
      float qr1[4] = {qv1.x, qv1.y, qv1.z, qv1.w};
      #pragma unroll
      for (int c = 0; c < 10; ++c) {
        float2 xv = *(const float2*)&x_lds[(cbase + c)*34 + nn]; // broadcast
        #pragma unroll
        for (int kk = 0; kk < 4; ++kk) {
          float a = acc[kk*10 + c];
          a = fmaf(qr0[kk], xv.x, a);
          a = fmaf(qr1[kk], xv.y, a);
          acc[kk*10 + c] = a;
        }
      }
    }
  }
  float* pp = part + ((size_t)((b*NT + nt)*5 + ct) * 40) * K;
  #pragma unroll
  for (int c = 0; c < 10; ++c) {
    float4 v = make_float4(acc[0*10+c], acc[1*10+c], acc[2*10+c], acc[3*10+c]);
    *(float4*)&pp[(size_t)(cbase + c)*K + k0] = v;
  }
}

// mass/spatial sums: mass[k] = sum_n Q[n][k], etc. grid = B*NTM, 128 n each.
__global__ __launch_bounds__(256) void k_mass(
    const float* __restrict__ Q, float* __restrict__ mpart) {
  int bid = blockIdx.x;             // B*NTM = 512
  int b = bid >> 7, nt = bid & 127;
  int tid = threadIdx.x;
  const float* Qb = Q + (size_t)b*N*K;
  int nbase = nt * 128;
  float mass = 0.f, sy = 0.f, sx = 0.f;
  for (int nn = 0; nn < 128; nn += 8) {
    float qv[8];
    #pragma unroll
    for (int j = 0; j < 8; ++j)
      qv[j] = Qb[(size_t)(nbase + nn + j)*K + tid];
    #pragma unroll
    for (int j = 0; j < 8; ++j) {
      int n = nbase + nn + j;
      mass += qv[j];
      sy += qv[j] * (float)(n >> 7);
      sx += qv[j] * (float)(n & 127);
    }
  }
  float* mp = mpart + (size_t)(b*NTM + nt) * 3 * K;
  mp[tid]       = mass;
  mp[K + tid]   = sy;
  mp[2*K + tid] = sx;
}

// stage 2: reduce NT partials per output element. grid = B*200.
__global__ __launch_bounds__(256) void k_reduce(
    const float* __restrict__ part, const float* __restrict__ mpart,
    float* __restrict__ sacc, float* __restrict__ macc,
    float* __restrict__ spacc) {
  int bid = blockIdx.x;        // B * 200
  int b = bid / 200;
  int r = bid % 200;
  int ct = r / 40, cw = r % 40;
  int tid = threadIdx.x;
  float s = 0.f;
  for (int nt = 0; nt < NT; ++nt)
    s += part[(((size_t)(b*NT + nt)*5 + ct)*40 + cw)*K + tid];
  sacc[(size_t)(b*K + tid)*C + ct*40 + cw] = s;
  if (r == 0) {
    float m = 0.f, yy = 0.f, xx = 0.f;
    for (int nt = 0; nt < NTM; ++nt) {
      const float* mp = mpart + (size_t)(b*NTM + nt) * 3 * K;
      m  += mp[tid];
      yy += mp[K + tid];
      xx += mp[2*K + tid];
    }
    macc[b*K + tid] = m;
    spacc[(b*K + tid)*2 + 0] = yy;
    spacc[(b*K + tid)*2 + 1] = xx;
  }
}

// ---------------------------------------------------------------------------
// fallback update (atomic version, used only if ws too small for partials)
__global__ __launch_bounds__(256, 2) void k_update(
    const float* __restrict__ x, const float* __restrict__ Q,
    float* __restrict__ sacc, float* __restrict__ macc,
    float* __restrict__ spacc) {
  __shared__ float x_lds[32*28];
  int bid = blockIdx.x;
  int b = bid >> 9;
  int rest = bid & 511;
  int ct = rest >> 6;
  int nt = rest & 63;
  int tid = threadIdx.x;
  int c0 = ct * 25;

  float acc[25];
  #pragma unroll
  for (int c = 0; c < 25; ++c) acc[c] = 0.f;
  float mass = 0.f, sy = 0.f, sx = 0.f;

  const float* xb = x + (size_t)b*C*N + (size_t)c0*N;
  const float* Qb = Q + (size_t)b*N*K;

  for (int ch = 0; ch < 8; ++ch) {
    int nb = nt*256 + ch*32;
    __syncthreads();
    #pragma unroll
    for (int pass = 0; pass < 4; ++pass) {
      int idx = pass*256 + tid;
      if (idx < 800) {
        int ci = idx >> 5, nn = idx & 31;
        x_lds[nn*28 + ci] = xb[(size_t)ci*N + nb + nn];
      }
    }
    __syncthreads();
    float py  = (float)(nb >> 7);
    float pxb = (float)(nb & 127);
    #pragma unroll
    for (int n4 = 0; n4 < 8; ++n4) {
      float qv[4];
      #pragma unroll
      for (int j = 0; j < 4; ++j)
        qv[j] = Qb[(size_t)(nb + n4*4 + j)*K + tid];
      #pragma unroll
      for (int j = 0; j < 4; ++j) {
        int nn = n4*4 + j;
        float q = qv[j];
        if (ct == 0) {
          mass += q;
          sy += q * py;
          sx += q * (pxb + (float)nn);
        }
        const float* xr = &x_lds[nn*28];
        #pragma unroll
        for (int c4 = 0; c4 < 6; ++c4) {
          float4 xv = *(const float4*)&xr[c4*4];
          acc[c4*4+0] = fmaf(q, xv.x, acc[c4*4+0]);
          acc[c4*4+1] = fmaf(q, xv.y, acc[c4*4+1]);
          acc[c4*4+2] = fmaf(q, xv.z, acc[c4*4+2]);
          acc[c4*4+3] = fmaf(q, xv.w, acc[c4*4+3]);
        }
        acc[24] = fmaf(q, xr[24], acc[24]);
      }
    }
  }
  float* sp = sacc + ((size_t)(b*K + tid))*C + c0;
  #pragma unroll
  for (int c = 0; c < 25; ++c) atomicAdd(&sp[c], acc[c]);
  if (ct == 0) {
    atomicAdd(&macc[b*K + tid], mass);
    atomicAdd(&spacc[(b*K + tid)*2 + 0], sy);
    atomicAdd(&spacc[(b*K + tid)*2 + 1], sx);
  }
}

// finalize: divide by mass; write centers (row-major + transposed) and d_out
__global__ void k_final(const float* __restrict__ sacc, const float* __restrict__ macc,
                        const float* __restrict__ spacc, float* __restrict__ cs,
                        float* __restrict__ cst, float* __restrict__ cspat,
                        float* __restrict__ outc, int last) {
  int bk = blockIdx.x;
  int b = bk >> 8, kk = bk & 255;
  int c = threadIdx.x;
  float inv = 1.f / (macc[bk] + 1e-6f);
  if (c < C) {
    float v = sacc[(size_t)bk*C + c] * inv;
    cs[(size_t)bk*C + c] = v;
    cst[((size_t)(b*C + c))*K + kk] = v;
    if (last) outc[(size_t)bk*C + c] = v;
  } else if (c == C) {
    cspat[bk*2 + 0] = spacc[bk*2 + 0] * inv;
  } else if (c == C + 1) {
    cspat[bk*2 + 1] = spacc[bk*2 + 1] * inv;
  }
}

extern "C" void kernel_launch(void* const* d_in, const int* in_sizes, int n_in,
                              void* d_out, int out_size, void* d_ws, size_t ws_size,
                              hipStream_t stream) {
  const float* x = (const float*)d_in[0];
  float* out = (float*)d_out;
  float* ws  = (float*)d_ws;
  float* a2    = ws + OFF_A2;
  float* cs    = ws + OFF_CS;
  float* cspat = ws + OFF_CSPAT;
  float* b2    = ws + OFF_B2;
  float* sacc  = ws + OFF_SACC;
  float* macc  = ws + OFF_MACC;
  float* spacc = ws + OFF_SPACC;
  float* cst   = ws + OFF_CST;
  float* part  = ws + OFF_PART;
  float* mpart = ws + OFF_MPART;
  float* outc  = out + (size_t)B*N*K;
  int split = (ws_size >= WS_NEED) ? 1 : 0;

  hipLaunchKernelGGL(k_init, dim3(K), dim3(256), 0, stream, x, cs, cst, cspat);
  hipLaunchKernelGGL(k_a2, dim3(B*64), dim3(256), 0, stream, x, a2);
  for (int it = 0; it < ITERS; ++it) {
    hipLaunchKernelGGL(k_b2, dim3(B*K), dim3(64), 0, stream, cs, b2);
    hipLaunchKernelGGL(k_assign, dim3(B*128), dim3(512), 0, stream,
                       x, cst, cspat, b2, a2, out);
    if (split) {
      hipLaunchKernelGGL(k_update3, dim3(B*5*NT), dim3(256), 0, stream,
                         x, out, part);
      hipLaunchKernelGGL(k_mass, dim3(B*NTM), dim3(256), 0, stream,
                         out, mpart);
      hipLaunchKernelGGL(k_reduce, dim3(B*200), dim3(256), 0, stream,
                         part, mpart, sacc, macc, spacc);
    } else {
      hipMemsetAsync(sacc, 0, (size_t)(B*K*C + B*K + B*K*2)*sizeof(float), stream);
      hipLaunchKernelGGL(k_update, dim3(B*512), dim3(256), 0, stream,
                         x, out, sacc, macc, spacc);
    }
    hipLaunchKernelGGL(k_final, dim3(B*K), dim3(256), 0, stream,
                       sacc, macc, spacc, cs, cst, cspat, outc,
                       (it == ITERS-1) ? 1 : 0);
  }
}